// Round 2
// baseline (2417.913 us; speedup 1.0000x reference)
//
#include <hip/hip_runtime.h>

// Problem constants
#define B_   256
#define T_   512
#define E_   200
#define H_   100
#define H3_  300
#define NC_  5

__device__ __forceinline__ void fma4(float4& acc, float a, const float4& w) {
    acc.x = fmaf(a, w.x, acc.x);
    acc.y = fmaf(a, w.y, acc.y);
    acc.z = fmaf(a, w.z, acc.z);
    acc.w = fmaf(a, w.w, acc.w);
}

// ---------------------------------------------------------------------------
// T0: pack weights: W_ihT[k][j] = W_ih[j][k]  (200x300)
//     wcat[k][j]: j<100 -> W_ti[j][k]; j==100 -> W_lgr[0][k]; else 0  (100x104)
// ---------------------------------------------------------------------------
__global__ void k_pack(const float* __restrict__ W_ih, const float* __restrict__ W_ti,
                       const float* __restrict__ W_lgr,
                       float* __restrict__ wT, float* __restrict__ wcat) {
    int idx = blockIdx.x * 256 + threadIdx.x;
    if (idx < E_ * H3_) {
        int k = idx / H3_, j = idx - k * H3_;
        wT[idx] = W_ih[j * E_ + k];
    }
    int i2 = idx - E_ * H3_;
    if (i2 >= 0 && i2 < H_ * 104) {
        int k = i2 / 104, j = i2 - k * 104;
        float v = 0.0f;
        if (j < H_) v = W_ti[j * H_ + k];
        else if (j == H_) v = W_lgr[k];
        wcat[i2] = v;
    }
}

// ---------------------------------------------------------------------------
// A: xp[row][j] = scale(row) * dot(emb[txt[row]], W_ih[j]) + b_ih[j]
// 32 rows/block, 320 threads: c = tid%80 (75 active, 4 cols each), g = tid/80 (8 rows)
// ---------------------------------------------------------------------------
__global__ __launch_bounds__(320) void k_embgemm(
        const int* __restrict__ txt, const float* __restrict__ emb,
        const float* __restrict__ wT, const float* __restrict__ b_ih,
        float* __restrict__ xp) {
    __shared__ __align__(16) float A_lds[E_ * 36];   // [k][r], stride 36 (28.8 KB)
    __shared__ __align__(16) float W_lds[32 * 320];  // [kk][j], stride 320 (40 KB)
    __shared__ float scale_lds[32];

    int tid = threadIdx.x;
    int base = blockIdx.x * 32;

    // stage A (raw emb rows), coalesced on k
    for (int idx = tid; idx < 32 * E_; idx += 320) {
        int r = idx / E_, k = idx - r * E_;
        int row = txt[base + r];
        A_lds[k * 36 + r] = emb[(size_t)row * E_ + k];
    }
    __syncthreads();

    // per-row norm -> scale
    if (tid < 32) {
        float ss = 0.0f;
        for (int k = 0; k < E_; ++k) { float v = A_lds[k * 36 + tid]; ss = fmaf(v, v, ss); }
        float n = sqrtf(ss);
        scale_lds[tid] = (n > 1.0f) ? (1.0f / (n + 1e-7f)) : 1.0f;
    }

    int c = tid % 80, g = tid / 80;
    float4 acc[8];
#pragma unroll
    for (int i = 0; i < 8; ++i) acc[i] = make_float4(0.f, 0.f, 0.f, 0.f);

    for (int kc = 0; kc < E_; kc += 32) {
        int KC = min(32, E_ - kc);
        __syncthreads();
        for (int idx = tid; idx < KC * H3_; idx += 320) {
            int kk = idx / H3_, j = idx - kk * H3_;
            W_lds[kk * 320 + j] = wT[(kc + kk) * H3_ + j];
        }
        __syncthreads();
        if (c < 75) {
            for (int kk = 0; kk < KC; ++kk) {
                int k = kc + kk;
                float4 wv = *(const float4*)&W_lds[kk * 320 + c * 4];
                float4 a0 = *(const float4*)&A_lds[k * 36 + g * 8];
                float4 a1 = *(const float4*)&A_lds[k * 36 + g * 8 + 4];
                fma4(acc[0], a0.x, wv); fma4(acc[1], a0.y, wv);
                fma4(acc[2], a0.z, wv); fma4(acc[3], a0.w, wv);
                fma4(acc[4], a1.x, wv); fma4(acc[5], a1.y, wv);
                fma4(acc[6], a1.z, wv); fma4(acc[7], a1.w, wv);
            }
        }
    }

    if (c < 75) {
        float4 bv = *(const float4*)&b_ih[c * 4];
#pragma unroll
        for (int rr = 0; rr < 8; ++rr) {
            int r = g * 8 + rr;
            float s = scale_lds[r];
            float4 res;
            res.x = fmaf(acc[rr].x, s, bv.x);
            res.y = fmaf(acc[rr].y, s, bv.y);
            res.z = fmaf(acc[rr].z, s, bv.z);
            res.w = fmaf(acc[rr].w, s, bv.w);
            *(float4*)&xp[(size_t)(base + r) * H3_ + c * 4] = res;
        }
    }
}

// ---------------------------------------------------------------------------
// B: GRU scan. 1 block per batch row, 128 threads (2 waves).
// Thread j<100 holds W_hh rows j, 100+j, 200+j in VGPRs (300 regs) and computes
// all three gates itself -> no hp round-trip. h double-buffered in LDS ->
// ONE barrier per step.
// ---------------------------------------------------------------------------
__global__ __launch_bounds__(128, 1) void k_gru(
        const float* __restrict__ xp, const float* __restrict__ W_hh,
        const float* __restrict__ b_hh, float* __restrict__ rnn) {
    __shared__ __align__(16) float hA[104];
    __shared__ __align__(16) float hB[104];

    int j = threadIdx.x;
    int b = blockIdx.x;

    float4 Wr[25], Wz[25], Wn[25];
    float bhr = 0.f, bhz = 0.f, bhn = 0.f;
    if (j < H_) {
        const float4* wr = (const float4*)(W_hh + (size_t)j * H_);
        const float4* wz = (const float4*)(W_hh + (size_t)(H_ + j) * H_);
        const float4* wn = (const float4*)(W_hh + (size_t)(2 * H_ + j) * H_);
#pragma unroll
        for (int kk = 0; kk < 25; ++kk) { Wr[kk] = wr[kk]; Wz[kk] = wz[kk]; Wn[kk] = wn[kk]; }
        bhr = b_hh[j]; bhz = b_hh[H_ + j]; bhn = b_hh[2 * H_ + j];
    }
    if (j < 104) hA[j] = 0.0f;
    float hown = 0.0f;

    const float* xpb = xp + (size_t)b * T_ * H3_;
    float* rnnb = rnn + (size_t)b * T_ * H_;
    float xr = 0.f, xz = 0.f, xn = 0.f;
    if (j < H_) { xr = xpb[j]; xz = xpb[H_ + j]; xn = xpb[2 * H_ + j]; }
    __syncthreads();

    float* rd = hA;
    float* wrb = hB;
    for (int t = 0; t < T_; ++t) {
        float r0 = bhr, r1 = 0.f, r2 = 0.f, r3 = 0.f;
        float z0 = bhz, z1 = 0.f, z2 = 0.f, z3 = 0.f;
        float n0 = bhn, n1 = 0.f, n2 = 0.f, n3 = 0.f;
        if (j < H_) {
#pragma unroll
            for (int kk = 0; kk < 25; ++kk) {
                float4 hv = *(const float4*)&rd[kk * 4];
                r0 = fmaf(Wr[kk].x, hv.x, r0); r1 = fmaf(Wr[kk].y, hv.y, r1);
                r2 = fmaf(Wr[kk].z, hv.z, r2); r3 = fmaf(Wr[kk].w, hv.w, r3);
                z0 = fmaf(Wz[kk].x, hv.x, z0); z1 = fmaf(Wz[kk].y, hv.y, z1);
                z2 = fmaf(Wz[kk].z, hv.z, z2); z3 = fmaf(Wz[kk].w, hv.w, z3);
                n0 = fmaf(Wn[kk].x, hv.x, n0); n1 = fmaf(Wn[kk].y, hv.y, n1);
                n2 = fmaf(Wn[kk].z, hv.z, n2); n3 = fmaf(Wn[kk].w, hv.w, n3);
            }
        }
        // prefetch next step's x while matvec is in flight
        float nxr = 0.f, nxz = 0.f, nxn = 0.f;
        if (j < H_ && t + 1 < T_) {
            const float* xq = xpb + (size_t)(t + 1) * H3_;
            nxr = xq[j]; nxz = xq[H_ + j]; nxn = xq[2 * H_ + j];
        }
        if (j < H_) {
            float hr = (r0 + r1) + (r2 + r3);
            float hz = (z0 + z1) + (z2 + z3);
            float hn = (n0 + n1) + (n2 + n3);
            float r = 1.0f / (1.0f + expf(-(xr + hr)));
            float z = 1.0f / (1.0f + expf(-(xz + hz)));
            float ng = tanhf(xn + r * hn);
            float hnew = (1.0f - z) * ng + z * hown;
            hown = hnew;
            wrb[j] = hnew;
            rnnb[(size_t)t * H_ + j] = hnew;
            xr = nxr; xz = nxz; xn = nxn;
        }
        __syncthreads();
        float* tmp = rd; rd = wrb; wrb = tmp;
    }
}

// ---------------------------------------------------------------------------
// C: ti = rnn @ W_ti.T + b_ti ; lgr = rnn @ W_lgr[:, :H].T ; z = relu(att*mask)
// ---------------------------------------------------------------------------
__global__ __launch_bounds__(256) void k_post(
        const float* __restrict__ rnn, const float* __restrict__ wcat,
        const float* __restrict__ b_ti, const int* __restrict__ lens,
        float* __restrict__ ti, float* __restrict__ lgr, float* __restrict__ zr) {
    __shared__ __align__(16) float A_lds[H_ * 72];   // [k][r], stride 72 (28.8 KB)
    __shared__ __align__(16) float W_lds[H_ * 112];  // [k][j], stride 112 (44.8 KB)

    int tid = threadIdx.x;
    int base = blockIdx.x * 64;

    for (int idx = tid; idx < 64 * H_; idx += 256) {
        int r = idx / H_, k = idx - r * H_;
        A_lds[k * 72 + r] = rnn[(size_t)(base + r) * H_ + k];
    }
    for (int idx = tid; idx < H_ * 104; idx += 256) {
        int k = idx / 104, jj = idx - k * 104;
        W_lds[k * 112 + jj] = wcat[idx];
    }
    __syncthreads();

    if (tid < 64) {
        float ss = 0.f, sm = 0.f;
        for (int k = 0; k < H_; ++k) {
            float v = A_lds[k * 72 + tid];
            ss = fmaf(v, v, ss); sm += v;
        }
        int row = base + tid;
        int bb = row >> 9, tt = row & 511;
        float att = sm / (fmaxf(sqrtf(ss), 1e-12f) * 1000.0f);  // / (norm * sqrt(H) * H)
        zr[row] = (tt < lens[bb]) ? fmaxf(att, 0.0f) : 0.0f;
    }

    int c = tid % 32, g = tid / 32;
    float4 acc[8];
#pragma unroll
    for (int i = 0; i < 8; ++i) acc[i] = make_float4(0.f, 0.f, 0.f, 0.f);

    if (c < 26) {
        for (int k = 0; k < H_; ++k) {
            float4 wv = *(const float4*)&W_lds[k * 112 + c * 4];
            float4 a0 = *(const float4*)&A_lds[k * 72 + g * 8];
            float4 a1 = *(const float4*)&A_lds[k * 72 + g * 8 + 4];
            fma4(acc[0], a0.x, wv); fma4(acc[1], a0.y, wv);
            fma4(acc[2], a0.z, wv); fma4(acc[3], a0.w, wv);
            fma4(acc[4], a1.x, wv); fma4(acc[5], a1.y, wv);
            fma4(acc[6], a1.z, wv); fma4(acc[7], a1.w, wv);
        }
    }

    if (c < 25) {
        float4 bv = *(const float4*)&b_ti[c * 4];
#pragma unroll
        for (int rr = 0; rr < 8; ++rr) {
            int row = base + g * 8 + rr;
            float4 res;
            res.x = acc[rr].x + bv.x; res.y = acc[rr].y + bv.y;
            res.z = acc[rr].z + bv.z; res.w = acc[rr].w + bv.w;
            *(float4*)&ti[(size_t)row * H_ + c * 4] = res;
        }
    } else if (c == 25) {
#pragma unroll
        for (int rr = 0; rr < 8; ++rr) {
            int row = base + g * 8 + rr;
            lgr[row] = acc[rr].x;  // j == 100 column
        }
    }
}

// ---------------------------------------------------------------------------
// D: rec scan + final GEMV. 1 block per batch row, 128 threads (2 waves).
// Thread j<100 holds W_ts row j AND the full W_lgr gate vector in VGPRs:
// gate dot computed redundantly per-thread -> no reduce, ONE barrier per step.
// ---------------------------------------------------------------------------
__global__ __launch_bounds__(128, 1) void k_rec(
        const float* __restrict__ ti, const float* __restrict__ lgr,
        const float* __restrict__ zr,
        const float* __restrict__ W_ts, const float* __restrict__ b_ts,
        const float* __restrict__ W_lgr, const float* __restrict__ b_lgr,
        const float* __restrict__ W_out, const float* __restrict__ b_out,
        float* __restrict__ out) {
    __shared__ __align__(16) float sA[104];
    __shared__ __align__(16) float sB[104];

    int j = threadIdx.x;
    int b = blockIdx.x;

    float4 Wt[25], Wl[25];
    float bts = 0.f;
    if (j < H_) {
        const float4* wr = (const float4*)(W_ts + (size_t)j * H_);
#pragma unroll
        for (int kk = 0; kk < 25; ++kk) Wt[kk] = wr[kk];
        bts = b_ts[j];
    }
#pragma unroll
    for (int kk = 0; kk < 25; ++kk) Wl[kk] = *(const float4*)&W_lgr[H_ + kk * 4];
    float blg = b_lgr[0];
    if (j < 104) sA[j] = 0.0f;
    float sown = 0.0f;

    size_t rb = (size_t)b * T_;
    float tiv = 0.f, zt = 0.f, lt = 0.f;
    if (j < H_) tiv = ti[rb * H_ + j];
    zt = zr[rb]; lt = lgr[rb];
    __syncthreads();

    float* rd = sA;
    float* wrb = sB;
    for (int t = 0; t < T_; ++t) {
        float a0 = 0.f, a1 = 0.f, a2 = 0.f, a3 = 0.f;
        float d0 = 0.f, d1 = 0.f, d2 = 0.f, d3 = 0.f;
        if (j < H_) {
#pragma unroll
            for (int kk = 0; kk < 25; ++kk) {
                float4 s4 = *(const float4*)&rd[kk * 4];
                a0 = fmaf(Wt[kk].x, s4.x, a0); a1 = fmaf(Wt[kk].y, s4.y, a1);
                a2 = fmaf(Wt[kk].z, s4.z, a2); a3 = fmaf(Wt[kk].w, s4.w, a3);
                d0 = fmaf(Wl[kk].x, s4.x, d0); d1 = fmaf(Wl[kk].y, s4.y, d1);
                d2 = fmaf(Wl[kk].z, s4.z, d2); d3 = fmaf(Wl[kk].w, s4.w, d3);
            }
        }
        // prefetch next step's inputs
        float ntiv = 0.f, nzt = 0.f, nlt = 0.f;
        if (t + 1 < T_) {
            if (j < H_) ntiv = ti[(rb + t + 1) * H_ + j];
            nzt = zr[rb + t + 1]; nlt = lgr[rb + t + 1];
        }
        if (j < H_) {
            float dot = (d0 + d1) + (d2 + d3);
            float sv  = (a0 + a1) + (a2 + a3);
            float gate = 1.0f / (1.0f + expf(-(lt + dot + blg)));
            float ns = tanhf(tiv + gate * sv + bts);
            float snew = (1.0f - zt) * sown + zt * ns;
            sown = snew;
            wrb[j] = snew;
        }
        tiv = ntiv; zt = nzt; lt = nlt;
        __syncthreads();
        float* tmp = rd; rd = wrb; wrb = tmp;
    }

    if (j < NC_) {
        float o = b_out[j];
        for (int k = 0; k < H_; ++k) o = fmaf(rd[k], W_out[j * H_ + k], o);
        out[b * NC_ + j] = o;
    }
}

// ---------------------------------------------------------------------------
extern "C" void kernel_launch(void* const* d_in, const int* in_sizes, int n_in,
                              void* d_out, int out_size, void* d_ws, size_t ws_size,
                              hipStream_t stream) {
    const int*   txt   = (const int*)d_in[0];
    const int*   lens  = (const int*)d_in[1];
    const float* emb   = (const float*)d_in[2];
    const float* W_ih  = (const float*)d_in[3];
    const float* W_hh  = (const float*)d_in[4];
    const float* b_ih  = (const float*)d_in[5];
    const float* b_hh  = (const float*)d_in[6];
    const float* W_lgr = (const float*)d_in[7];
    const float* b_lgr = (const float*)d_in[8];
    const float* W_ts  = (const float*)d_in[9];
    const float* b_ts  = (const float*)d_in[10];
    const float* W_ti  = (const float*)d_in[11];
    const float* b_ti  = (const float*)d_in[12];
    const float* W_out = (const float*)d_in[13];
    const float* b_out = (const float*)d_in[14];

    float* ws   = (float*)d_ws;
    float* xp   = ws;                    // 39,321,600 floats (157 MB)
    float* rnn  = xp + 39321600;         // 13,107,200 floats (52 MB)
    float* lgrv = rnn + 13107200;        // 131,072
    float* zrv  = lgrv + 131072;         // 131,072
    float* wT   = zrv + 131072;          // 60,000
    float* wcat = wT + 60000;            // 10,400
    float* ti   = xp;                    // reuse xp region after GRU

    float* out = (float*)d_out;

    k_pack<<<276, 256, 0, stream>>>(W_ih, W_ti, W_lgr, wT, wcat);
    k_embgemm<<<4096, 320, 0, stream>>>(txt, emb, wT, b_ih, xp);
    k_gru<<<256, 128, 0, stream>>>(xp, W_hh, b_hh, rnn);
    k_post<<<2048, 256, 0, stream>>>(rnn, wcat, b_ti, lens, ti, lgrv, zrv);
    k_rec<<<256, 128, 0, stream>>>(ti, lgrv, zrv, W_ts, b_ts, W_lgr, b_lgr,
                                   W_out, b_out, out);
}

// Round 3
// 2167.485 us; speedup vs baseline: 1.1155x; 1.1155x over previous
//
#include <hip/hip_runtime.h>

// Problem constants
#define B_   256
#define T_   512
#define E_   200
#define H_   100
#define H3_  300
#define NC_  5

__device__ __forceinline__ void fma4(float4& acc, float a, const float4& w) {
    acc.x = fmaf(a, w.x, acc.x);
    acc.y = fmaf(a, w.y, acc.y);
    acc.z = fmaf(a, w.z, acc.z);
    acc.w = fmaf(a, w.w, acc.w);
}

// ---------------------------------------------------------------------------
// T0: pack weights: W_ihT[k][j] = W_ih[j][k]  (200x300)
//     wcat[k][j]: j<100 -> W_ti[j][k]; j==100 -> W_lgr[0][k]; else 0  (100x104)
// ---------------------------------------------------------------------------
__global__ void k_pack(const float* __restrict__ W_ih, const float* __restrict__ W_ti,
                       const float* __restrict__ W_lgr,
                       float* __restrict__ wT, float* __restrict__ wcat) {
    int idx = blockIdx.x * 256 + threadIdx.x;
    if (idx < E_ * H3_) {
        int k = idx / H3_, j = idx - k * H3_;
        wT[idx] = W_ih[j * E_ + k];
    }
    int i2 = idx - E_ * H3_;
    if (i2 >= 0 && i2 < H_ * 104) {
        int k = i2 / 104, j = i2 - k * 104;
        float v = 0.0f;
        if (j < H_) v = W_ti[j * H_ + k];
        else if (j == H_) v = W_lgr[k];
        wcat[i2] = v;
    }
}

// ---------------------------------------------------------------------------
// A: xp[row][j] = scale(row) * dot(emb[txt[row]], W_ih[j]) + b_ih[j]
// 32 rows/block, 320 threads: c = tid%80 (75 active, 4 cols each), g = tid/80 (8 rows)
// ---------------------------------------------------------------------------
__global__ __launch_bounds__(320) void k_embgemm(
        const int* __restrict__ txt, const float* __restrict__ emb,
        const float* __restrict__ wT, const float* __restrict__ b_ih,
        float* __restrict__ xp) {
    __shared__ __align__(16) float A_lds[E_ * 36];   // [k][r], stride 36 (28.8 KB)
    __shared__ __align__(16) float W_lds[32 * 320];  // [kk][j], stride 320 (40 KB)
    __shared__ float scale_lds[32];

    int tid = threadIdx.x;
    int base = blockIdx.x * 32;

    // stage A (raw emb rows), coalesced on k
    for (int idx = tid; idx < 32 * E_; idx += 320) {
        int r = idx / E_, k = idx - r * E_;
        int row = txt[base + r];
        A_lds[k * 36 + r] = emb[(size_t)row * E_ + k];
    }
    __syncthreads();

    // per-row norm -> scale
    if (tid < 32) {
        float ss = 0.0f;
        for (int k = 0; k < E_; ++k) { float v = A_lds[k * 36 + tid]; ss = fmaf(v, v, ss); }
        float n = sqrtf(ss);
        scale_lds[tid] = (n > 1.0f) ? (1.0f / (n + 1e-7f)) : 1.0f;
    }

    int c = tid % 80, g = tid / 80;
    float4 acc[8];
#pragma unroll
    for (int i = 0; i < 8; ++i) acc[i] = make_float4(0.f, 0.f, 0.f, 0.f);

    for (int kc = 0; kc < E_; kc += 32) {
        int KC = min(32, E_ - kc);
        __syncthreads();
        for (int idx = tid; idx < KC * H3_; idx += 320) {
            int kk = idx / H3_, j = idx - kk * H3_;
            W_lds[kk * 320 + j] = wT[(kc + kk) * H3_ + j];
        }
        __syncthreads();
        if (c < 75) {
            for (int kk = 0; kk < KC; ++kk) {
                int k = kc + kk;
                float4 wv = *(const float4*)&W_lds[kk * 320 + c * 4];
                float4 a0 = *(const float4*)&A_lds[k * 36 + g * 8];
                float4 a1 = *(const float4*)&A_lds[k * 36 + g * 8 + 4];
                fma4(acc[0], a0.x, wv); fma4(acc[1], a0.y, wv);
                fma4(acc[2], a0.z, wv); fma4(acc[3], a0.w, wv);
                fma4(acc[4], a1.x, wv); fma4(acc[5], a1.y, wv);
                fma4(acc[6], a1.z, wv); fma4(acc[7], a1.w, wv);
            }
        }
    }

    if (c < 75) {
        float4 bv = *(const float4*)&b_ih[c * 4];
#pragma unroll
        for (int rr = 0; rr < 8; ++rr) {
            int r = g * 8 + rr;
            float s = scale_lds[r];
            float4 res;
            res.x = fmaf(acc[rr].x, s, bv.x);
            res.y = fmaf(acc[rr].y, s, bv.y);
            res.z = fmaf(acc[rr].z, s, bv.z);
            res.w = fmaf(acc[rr].w, s, bv.w);
            *(float4*)&xp[(size_t)(base + r) * H3_ + c * 4] = res;
        }
    }
}

// ---------------------------------------------------------------------------
// B: GRU scan. 1 block per batch row, 320 threads (5 waves).
// Thread j<300 holds ONE W_hh row (100 floats) in VGPRs — launch_bounds(320,1)
// unlocks the full VGPR budget so the array is NOT spilled (grid == 1 block/CU
// anyway, so capping occupancy is free). Two barriers/step via hp_lds.
// ---------------------------------------------------------------------------
__global__ __launch_bounds__(320, 1) void k_gru(
        const float* __restrict__ xp, const float* __restrict__ W_hh,
        const float* __restrict__ b_hh, float* __restrict__ rnn) {
    __shared__ __align__(16) float h_lds[104];
    __shared__ float hp_lds[H3_];

    int j = threadIdx.x;
    int b = blockIdx.x;

    float4 W4[25];
    float bh = 0.0f;
    if (j < H3_) {
        const float4* wr = (const float4*)(W_hh + (size_t)j * H_);
#pragma unroll
        for (int kk = 0; kk < 25; ++kk) W4[kk] = wr[kk];
        bh = b_hh[j];
    }
    if (j < 104) h_lds[j] = 0.0f;
    float hown = 0.0f;  // thread j<100 keeps its own h[j]

    const float* xpb = xp + (size_t)b * T_ * H3_;
    float* rnnb = rnn + (size_t)b * T_ * H_;
    float xr = 0.f, xz = 0.f, xn = 0.f;
    if (j < H_) { xr = xpb[j]; xz = xpb[H_ + j]; xn = xpb[2 * H_ + j]; }
    __syncthreads();

    for (int t = 0; t < T_; ++t) {
        float acc0 = bh, acc1 = 0.f, acc2 = 0.f, acc3 = 0.f;
        if (j < H3_) {
#pragma unroll
            for (int kk = 0; kk < 25; ++kk) {
                float4 hv = *(const float4*)&h_lds[kk * 4];  // broadcast read
                acc0 = fmaf(W4[kk].x, hv.x, acc0);
                acc1 = fmaf(W4[kk].y, hv.y, acc1);
                acc2 = fmaf(W4[kk].z, hv.z, acc2);
                acc3 = fmaf(W4[kk].w, hv.w, acc3);
            }
            hp_lds[j] = (acc0 + acc1) + (acc2 + acc3);
        }
        // prefetch next step's x while matvec is in flight
        float nxr = 0.f, nxz = 0.f, nxn = 0.f;
        if (j < H_ && t + 1 < T_) {
            const float* xq = xpb + (size_t)(t + 1) * H3_;
            nxr = xq[j]; nxz = xq[H_ + j]; nxn = xq[2 * H_ + j];
        }
        __syncthreads();
        if (j < H_) {
            float hr = hp_lds[j], hz = hp_lds[H_ + j], hn = hp_lds[2 * H_ + j];
            float r = 1.0f / (1.0f + expf(-(xr + hr)));
            float z = 1.0f / (1.0f + expf(-(xz + hz)));
            float ng = tanhf(xn + r * hn);
            float hnew = (1.0f - z) * ng + z * hown;
            hown = hnew;
            h_lds[j] = hnew;
            rnnb[(size_t)t * H_ + j] = hnew;
            xr = nxr; xz = nxz; xn = nxn;
        }
        __syncthreads();
    }
}

// ---------------------------------------------------------------------------
// C: ti = rnn @ W_ti.T + b_ti ; lgr = rnn @ W_lgr[:, :H].T ; z = relu(att*mask)
// ---------------------------------------------------------------------------
__global__ __launch_bounds__(256) void k_post(
        const float* __restrict__ rnn, const float* __restrict__ wcat,
        const float* __restrict__ b_ti, const int* __restrict__ lens,
        float* __restrict__ ti, float* __restrict__ lgr, float* __restrict__ zr) {
    __shared__ __align__(16) float A_lds[H_ * 72];   // [k][r], stride 72 (28.8 KB)
    __shared__ __align__(16) float W_lds[H_ * 112];  // [k][j], stride 112 (44.8 KB)

    int tid = threadIdx.x;
    int base = blockIdx.x * 64;

    for (int idx = tid; idx < 64 * H_; idx += 256) {
        int r = idx / H_, k = idx - r * H_;
        A_lds[k * 72 + r] = rnn[(size_t)(base + r) * H_ + k];
    }
    for (int idx = tid; idx < H_ * 104; idx += 256) {
        int k = idx / 104, jj = idx - k * 104;
        W_lds[k * 112 + jj] = wcat[idx];
    }
    __syncthreads();

    if (tid < 64) {
        float ss = 0.f, sm = 0.f;
        for (int k = 0; k < H_; ++k) {
            float v = A_lds[k * 72 + tid];
            ss = fmaf(v, v, ss); sm += v;
        }
        int row = base + tid;
        int bb = row >> 9, tt = row & 511;
        float att = sm / (fmaxf(sqrtf(ss), 1e-12f) * 1000.0f);  // / (norm * sqrt(H) * H)
        zr[row] = (tt < lens[bb]) ? fmaxf(att, 0.0f) : 0.0f;
    }

    int c = tid % 32, g = tid / 32;
    float4 acc[8];
#pragma unroll
    for (int i = 0; i < 8; ++i) acc[i] = make_float4(0.f, 0.f, 0.f, 0.f);

    if (c < 26) {
        for (int k = 0; k < H_; ++k) {
            float4 wv = *(const float4*)&W_lds[k * 112 + c * 4];
            float4 a0 = *(const float4*)&A_lds[k * 72 + g * 8];
            float4 a1 = *(const float4*)&A_lds[k * 72 + g * 8 + 4];
            fma4(acc[0], a0.x, wv); fma4(acc[1], a0.y, wv);
            fma4(acc[2], a0.z, wv); fma4(acc[3], a0.w, wv);
            fma4(acc[4], a1.x, wv); fma4(acc[5], a1.y, wv);
            fma4(acc[6], a1.z, wv); fma4(acc[7], a1.w, wv);
        }
    }

    if (c < 25) {
        float4 bv = *(const float4*)&b_ti[c * 4];
#pragma unroll
        for (int rr = 0; rr < 8; ++rr) {
            int row = base + g * 8 + rr;
            float4 res;
            res.x = acc[rr].x + bv.x; res.y = acc[rr].y + bv.y;
            res.z = acc[rr].z + bv.z; res.w = acc[rr].w + bv.w;
            *(float4*)&ti[(size_t)row * H_ + c * 4] = res;
        }
    } else if (c == 25) {
#pragma unroll
        for (int rr = 0; rr < 8; ++rr) {
            int row = base + g * 8 + rr;
            lgr[row] = acc[rr].x;  // j == 100 column
        }
    }
}

// ---------------------------------------------------------------------------
// D: rec scan + final GEMV. 1 block per batch row, 128 threads (2 waves).
// Thread j<100 holds W_ts row j (100 floats) in VGPRs; the wave-uniform W_lgr
// gate vector lives in LDS (broadcast b128 reads) so register demand is ~130
// and nothing spills. Gate dot computed redundantly per-thread -> no reduce,
// ONE barrier per step (state double-buffered).
// ---------------------------------------------------------------------------
__global__ __launch_bounds__(128, 1) void k_rec(
        const float* __restrict__ ti, const float* __restrict__ lgr,
        const float* __restrict__ zr,
        const float* __restrict__ W_ts, const float* __restrict__ b_ts,
        const float* __restrict__ W_lgr, const float* __restrict__ b_lgr,
        const float* __restrict__ W_out, const float* __restrict__ b_out,
        float* __restrict__ out) {
    __shared__ __align__(16) float sA[104];
    __shared__ __align__(16) float sB[104];
    __shared__ __align__(16) float wl_lds[104];

    int j = threadIdx.x;
    int b = blockIdx.x;

    float4 Wt[25];
    float bts = 0.f;
    if (j < H_) {
        const float4* wr = (const float4*)(W_ts + (size_t)j * H_);
#pragma unroll
        for (int kk = 0; kk < 25; ++kk) Wt[kk] = wr[kk];
        bts = b_ts[j];
    }
    if (j < 104) {
        wl_lds[j] = (j < H_) ? W_lgr[H_ + j] : 0.0f;
        sA[j] = 0.0f;
    }
    float blg = b_lgr[0];
    float sown = 0.0f;

    size_t rb = (size_t)b * T_;
    float tiv = 0.f, zt = 0.f, lt = 0.f;
    if (j < H_) tiv = ti[rb * H_ + j];
    zt = zr[rb]; lt = lgr[rb];
    __syncthreads();

    float* rd = sA;
    float* wrb = sB;
    for (int t = 0; t < T_; ++t) {
        float a0 = 0.f, a1 = 0.f, a2 = 0.f, a3 = 0.f;
        float d0 = 0.f, d1 = 0.f, d2 = 0.f, d3 = 0.f;
        if (j < H_) {
#pragma unroll
            for (int kk = 0; kk < 25; ++kk) {
                float4 s4 = *(const float4*)&rd[kk * 4];       // broadcast
                float4 w4 = *(const float4*)&wl_lds[kk * 4];   // broadcast
                a0 = fmaf(Wt[kk].x, s4.x, a0); a1 = fmaf(Wt[kk].y, s4.y, a1);
                a2 = fmaf(Wt[kk].z, s4.z, a2); a3 = fmaf(Wt[kk].w, s4.w, a3);
                d0 = fmaf(w4.x, s4.x, d0); d1 = fmaf(w4.y, s4.y, d1);
                d2 = fmaf(w4.z, s4.z, d2); d3 = fmaf(w4.w, s4.w, d3);
            }
        }
        // prefetch next step's inputs
        float ntiv = 0.f, nzt = 0.f, nlt = 0.f;
        if (t + 1 < T_) {
            if (j < H_) ntiv = ti[(rb + t + 1) * H_ + j];
            nzt = zr[rb + t + 1]; nlt = lgr[rb + t + 1];
        }
        if (j < H_) {
            float dot = (d0 + d1) + (d2 + d3);
            float sv  = (a0 + a1) + (a2 + a3);
            float gate = 1.0f / (1.0f + expf(-(lt + dot + blg)));
            float ns = tanhf(tiv + gate * sv + bts);
            float snew = (1.0f - zt) * sown + zt * ns;
            sown = snew;
            wrb[j] = snew;
        }
        tiv = ntiv; zt = nzt; lt = nlt;
        __syncthreads();
        float* tmp = rd; rd = wrb; wrb = tmp;
    }

    if (j < NC_) {
        float o = b_out[j];
        for (int k = 0; k < H_; ++k) o = fmaf(rd[k], W_out[j * H_ + k], o);
        out[b * NC_ + j] = o;
    }
}

// ---------------------------------------------------------------------------
extern "C" void kernel_launch(void* const* d_in, const int* in_sizes, int n_in,
                              void* d_out, int out_size, void* d_ws, size_t ws_size,
                              hipStream_t stream) {
    const int*   txt   = (const int*)d_in[0];
    const int*   lens  = (const int*)d_in[1];
    const float* emb   = (const float*)d_in[2];
    const float* W_ih  = (const float*)d_in[3];
    const float* W_hh  = (const float*)d_in[4];
    const float* b_ih  = (const float*)d_in[5];
    const float* b_hh  = (const float*)d_in[6];
    const float* W_lgr = (const float*)d_in[7];
    const float* b_lgr = (const float*)d_in[8];
    const float* W_ts  = (const float*)d_in[9];
    const float* b_ts  = (const float*)d_in[10];
    const float* W_ti  = (const float*)d_in[11];
    const float* b_ti  = (const float*)d_in[12];
    const float* W_out = (const float*)d_in[13];
    const float* b_out = (const float*)d_in[14];

    float* ws   = (float*)d_ws;
    float* xp   = ws;                    // 39,321,600 floats (157 MB)
    float* rnn  = xp + 39321600;         // 13,107,200 floats (52 MB)
    float* lgrv = rnn + 13107200;        // 131,072
    float* zrv  = lgrv + 131072;         // 131,072
    float* wT   = zrv + 131072;          // 60,000
    float* wcat = wT + 60000;            // 10,400
    float* ti   = xp;                    // reuse xp region after GRU

    float* out = (float*)d_out;

    k_pack<<<276, 256, 0, stream>>>(W_ih, W_ti, W_lgr, wT, wcat);
    k_embgemm<<<4096, 320, 0, stream>>>(txt, emb, wT, b_ih, xp);
    k_gru<<<256, 320, 0, stream>>>(xp, W_hh, b_hh, rnn);
    k_post<<<2048, 256, 0, stream>>>(rnn, wcat, b_ti, lens, ti, lgrv, zrv);
    k_rec<<<256, 128, 0, stream>>>(ti, lgrv, zrv, W_ts, b_ts, W_lgr, b_lgr,
                                   W_out, b_out, out);
}

// Round 5
// 1970.553 us; speedup vs baseline: 1.2270x; 1.0999x over previous
//
#include <hip/hip_runtime.h>

// Problem constants
#define B_   256
#define T_   512
#define E_   200
#define H_   100
#define H3_  300
#define NC_  5

__device__ __forceinline__ void fma4(float4& acc, float a, const float4& w) {
    acc.x = fmaf(a, w.x, acc.x);
    acc.y = fmaf(a, w.y, acc.y);
    acc.z = fmaf(a, w.z, acc.z);
    acc.w = fmaf(a, w.w, acc.w);
}

// Light barrier: drain LDS ops only (NOT global/vmcnt), then raw s_barrier.
// __syncthreads() would emit s_waitcnt vmcnt(0) and put HBM store/prefetch
// latency on the scan critical path every step.
__device__ __forceinline__ void ldsbar() {
    asm volatile("s_waitcnt lgkmcnt(0)" ::: "memory");
    __builtin_amdgcn_s_barrier();
    __builtin_amdgcn_sched_barrier(0);
}

// ---------------------------------------------------------------------------
// T0: pack weights: W_ihT[k][j] = W_ih[j][k]  (200x300)
//     wcat[k][j]: j<100 -> W_ti[j][k]; j==100 -> W_lgr[0][k]; else 0  (100x104)
// ---------------------------------------------------------------------------
__global__ void k_pack(const float* __restrict__ W_ih, const float* __restrict__ W_ti,
                       const float* __restrict__ W_lgr,
                       float* __restrict__ wT, float* __restrict__ wcat) {
    int idx = blockIdx.x * 256 + threadIdx.x;
    if (idx < E_ * H3_) {
        int k = idx / H3_, j = idx - k * H3_;
        wT[idx] = W_ih[j * E_ + k];
    }
    int i2 = idx - E_ * H3_;
    if (i2 >= 0 && i2 < H_ * 104) {
        int k = i2 / 104, j = i2 - k * 104;
        float v = 0.0f;
        if (j < H_) v = W_ti[j * H_ + k];
        else if (j == H_) v = W_lgr[k];
        wcat[i2] = v;
    }
}

// ---------------------------------------------------------------------------
// A: xp[row][j] = scale(row) * dot(emb[txt[row]], W_ih[j]) + b_ih[j]
// ---------------------------------------------------------------------------
__global__ __launch_bounds__(320) void k_embgemm(
        const int* __restrict__ txt, const float* __restrict__ emb,
        const float* __restrict__ wT, const float* __restrict__ b_ih,
        float* __restrict__ xp) {
    __shared__ __align__(16) float A_lds[E_ * 36];   // [k][r], stride 36 (28.8 KB)
    __shared__ __align__(16) float W_lds[32 * 320];  // [kk][j], stride 320 (40 KB)
    __shared__ float scale_lds[32];

    int tid = threadIdx.x;
    int base = blockIdx.x * 32;

    for (int idx = tid; idx < 32 * E_; idx += 320) {
        int r = idx / E_, k = idx - r * E_;
        int row = txt[base + r];
        A_lds[k * 36 + r] = emb[(size_t)row * E_ + k];
    }
    __syncthreads();

    if (tid < 32) {
        float ss = 0.0f;
        for (int k = 0; k < E_; ++k) { float v = A_lds[k * 36 + tid]; ss = fmaf(v, v, ss); }
        float n = sqrtf(ss);
        scale_lds[tid] = (n > 1.0f) ? (1.0f / (n + 1e-7f)) : 1.0f;
    }

    int c = tid % 80, g = tid / 80;
    float4 acc[8];
#pragma unroll
    for (int i = 0; i < 8; ++i) acc[i] = make_float4(0.f, 0.f, 0.f, 0.f);

    for (int kc = 0; kc < E_; kc += 32) {
        int KC = min(32, E_ - kc);
        __syncthreads();
        for (int idx = tid; idx < KC * H3_; idx += 320) {
            int kk = idx / H3_, j = idx - kk * H3_;
            W_lds[kk * 320 + j] = wT[(kc + kk) * H3_ + j];
        }
        __syncthreads();
        if (c < 75) {
            for (int kk = 0; kk < KC; ++kk) {
                int k = kc + kk;
                float4 wv = *(const float4*)&W_lds[kk * 320 + c * 4];
                float4 a0 = *(const float4*)&A_lds[k * 36 + g * 8];
                float4 a1 = *(const float4*)&A_lds[k * 36 + g * 8 + 4];
                fma4(acc[0], a0.x, wv); fma4(acc[1], a0.y, wv);
                fma4(acc[2], a0.z, wv); fma4(acc[3], a0.w, wv);
                fma4(acc[4], a1.x, wv); fma4(acc[5], a1.y, wv);
                fma4(acc[6], a1.z, wv); fma4(acc[7], a1.w, wv);
            }
        }
    }

    if (c < 75) {
        float4 bv = *(const float4*)&b_ih[c * 4];
#pragma unroll
        for (int rr = 0; rr < 8; ++rr) {
            int r = g * 8 + rr;
            float s = scale_lds[r];
            float4 res;
            res.x = fmaf(acc[rr].x, s, bv.x);
            res.y = fmaf(acc[rr].y, s, bv.y);
            res.z = fmaf(acc[rr].z, s, bv.z);
            res.w = fmaf(acc[rr].w, s, bv.w);
            *(float4*)&xp[(size_t)(base + r) * H3_ + c * 4] = res;
        }
    }
}

// ---------------------------------------------------------------------------
// B: GRU scan. 1 block per batch row, 320 threads (5 waves).
// Thread j<300 holds ONE W_hh row (100 floats) in VGPRs. Two LIGHT barriers
// per step (lgkmcnt-only): the rnn global store and the x prefetch loads stay
// in flight across barriers and are waited only at use (one step later).
// ---------------------------------------------------------------------------
__global__ __launch_bounds__(320, 1) void k_gru(
        const float* __restrict__ xp, const float* __restrict__ W_hh,
        const float* __restrict__ b_hh, float* __restrict__ rnn) {
    __shared__ __align__(16) float h_lds[104];
    __shared__ float hp_lds[H3_];

    int j = threadIdx.x;
    int b = blockIdx.x;

    float4 W4[25];
    float bh = 0.0f;
    if (j < H3_) {
        const float4* wr = (const float4*)(W_hh + (size_t)j * H_);
#pragma unroll
        for (int kk = 0; kk < 25; ++kk) W4[kk] = wr[kk];
        bh = b_hh[j];
    }
    if (j < 104) h_lds[j] = 0.0f;
    float hown = 0.0f;  // thread j<100 keeps its own h[j]

    const float* xpb = xp + (size_t)b * T_ * H3_;
    float* rnnb = rnn + (size_t)b * T_ * H_;
    float xr = 0.f, xz = 0.f, xn = 0.f;
    if (j < H_) { xr = xpb[j]; xz = xpb[H_ + j]; xn = xpb[2 * H_ + j]; }
    __syncthreads();

    for (int t = 0; t < T_; ++t) {
        float acc0 = bh, acc1 = 0.f, acc2 = 0.f, acc3 = 0.f;
        if (j < H3_) {
#pragma unroll
            for (int kk = 0; kk < 25; ++kk) {
                float4 hv = *(const float4*)&h_lds[kk * 4];  // broadcast read
                acc0 = fmaf(W4[kk].x, hv.x, acc0);
                acc1 = fmaf(W4[kk].y, hv.y, acc1);
                acc2 = fmaf(W4[kk].z, hv.z, acc2);
                acc3 = fmaf(W4[kk].w, hv.w, acc3);
            }
            hp_lds[j] = (acc0 + acc1) + (acc2 + acc3);
        }
        // prefetch next step's x while matvec/barrier are in flight
        float nxr = 0.f, nxz = 0.f, nxn = 0.f;
        if (j < H_ && t + 1 < T_) {
            const float* xq = xpb + (size_t)(t + 1) * H3_;
            nxr = xq[j]; nxz = xq[H_ + j]; nxn = xq[2 * H_ + j];
        }
        ldsbar();  // hp visible
        if (j < H_) {
            float hr = hp_lds[j], hz = hp_lds[H_ + j], hn = hp_lds[2 * H_ + j];
            float r = 1.0f / (1.0f + expf(-(xr + hr)));
            float z = 1.0f / (1.0f + expf(-(xz + hz)));
            float ng = tanhf(xn + r * hn);
            float hnew = (1.0f - z) * ng + z * hown;
            hown = hnew;
            h_lds[j] = hnew;
            rnnb[(size_t)t * H_ + j] = hnew;   // fire-and-forget (not drained)
            xr = nxr; xz = nxz; xn = nxn;
        }
        ldsbar();  // h visible for next matvec
    }
}

// ---------------------------------------------------------------------------
// C: ti = rnn @ W_ti.T + b_ti ; lgr = rnn @ W_lgr[:, :H].T ; z = relu(att*mask)
// ---------------------------------------------------------------------------
__global__ __launch_bounds__(256) void k_post(
        const float* __restrict__ rnn, const float* __restrict__ wcat,
        const float* __restrict__ b_ti, const int* __restrict__ lens,
        float* __restrict__ ti, float* __restrict__ lgr, float* __restrict__ zr) {
    __shared__ __align__(16) float A_lds[H_ * 72];   // [k][r], stride 72 (28.8 KB)
    __shared__ __align__(16) float W_lds[H_ * 112];  // [k][j], stride 112 (44.8 KB)

    int tid = threadIdx.x;
    int base = blockIdx.x * 64;

    for (int idx = tid; idx < 64 * H_; idx += 256) {
        int r = idx / H_, k = idx - r * H_;
        A_lds[k * 72 + r] = rnn[(size_t)(base + r) * H_ + k];
    }
    for (int idx = tid; idx < H_ * 104; idx += 256) {
        int k = idx / 104, jj = idx - k * 104;
        W_lds[k * 112 + jj] = wcat[idx];
    }
    __syncthreads();

    if (tid < 64) {
        float ss = 0.f, sm = 0.f;
        for (int k = 0; k < H_; ++k) {
            float v = A_lds[k * 72 + tid];
            ss = fmaf(v, v, ss); sm += v;
        }
        int row = base + tid;
        int bb = row >> 9, tt = row & 511;
        float att = sm / (fmaxf(sqrtf(ss), 1e-12f) * 1000.0f);  // / (norm * sqrt(H) * H)
        zr[row] = (tt < lens[bb]) ? fmaxf(att, 0.0f) : 0.0f;
    }

    int c = tid % 32, g = tid / 32;
    float4 acc[8];
#pragma unroll
    for (int i = 0; i < 8; ++i) acc[i] = make_float4(0.f, 0.f, 0.f, 0.f);

    if (c < 26) {
        for (int k = 0; k < H_; ++k) {
            float4 wv = *(const float4*)&W_lds[k * 112 + c * 4];
            float4 a0 = *(const float4*)&A_lds[k * 72 + g * 8];
            float4 a1 = *(const float4*)&A_lds[k * 72 + g * 8 + 4];
            fma4(acc[0], a0.x, wv); fma4(acc[1], a0.y, wv);
            fma4(acc[2], a0.z, wv); fma4(acc[3], a0.w, wv);
            fma4(acc[4], a1.x, wv); fma4(acc[5], a1.y, wv);
            fma4(acc[6], a1.z, wv); fma4(acc[7], a1.w, wv);
        }
    }

    if (c < 25) {
        float4 bv = *(const float4*)&b_ti[c * 4];
#pragma unroll
        for (int rr = 0; rr < 8; ++rr) {
            int row = base + g * 8 + rr;
            float4 res;
            res.x = acc[rr].x + bv.x; res.y = acc[rr].y + bv.y;
            res.z = acc[rr].z + bv.z; res.w = acc[rr].w + bv.w;
            *(float4*)&ti[(size_t)row * H_ + c * 4] = res;
        }
    } else if (c == 25) {
#pragma unroll
        for (int rr = 0; rr < 8; ++rr) {
            int row = base + g * 8 + rr;
            lgr[row] = acc[rr].x;  // j == 100 column
        }
    }
}

// ---------------------------------------------------------------------------
// D: rec scan + final GEMV. 1 block per batch row, 128 threads (2 waves).
// Thread j<100 holds W_ts row j (100 floats) + wl_j (1 float) in VGPRs.
// Gate dot wl·s is PIPELINED: computed at step end from snew via shfl_xor
// tree + per-wave LDS slot, merged into the single light barrier. Parity-
// double-buffered red[] avoids the cross-wave WAR race.
// ---------------------------------------------------------------------------
__global__ __launch_bounds__(128, 1) void k_rec(
        const float* __restrict__ ti, const float* __restrict__ lgr,
        const float* __restrict__ zr,
        const float* __restrict__ W_ts, const float* __restrict__ b_ts,
        const float* __restrict__ W_lgr, const float* __restrict__ b_lgr,
        const float* __restrict__ W_out, const float* __restrict__ b_out,
        float* __restrict__ out) {
    __shared__ __align__(16) float sA[104];
    __shared__ __align__(16) float sB[104];
    __shared__ float red[2][2];   // [parity][wave]

    int j = threadIdx.x;
    int b = blockIdx.x;
    int wave = j >> 6;

    float4 Wt[25];
    float bts = 0.f, wlj = 0.f;
    if (j < H_) {
        const float4* wr = (const float4*)(W_ts + (size_t)j * H_);
#pragma unroll
        for (int kk = 0; kk < 25; ++kk) Wt[kk] = wr[kk];
        bts = b_ts[j];
        wlj = W_lgr[H_ + j];
    }
    if (j < 104) { sA[j] = 0.0f; }
    if (j < 4) ((float*)red)[j] = 0.0f;
    float blg = b_lgr[0];
    float sown = 0.0f;

    size_t rb = (size_t)b * T_;
    float tiv = 0.f, zt = 0.f, lt = 0.f;
    if (j < H_) tiv = ti[rb * H_ + j];
    zt = zr[rb]; lt = lgr[rb];
    __syncthreads();

    float* rd = sA;
    float* wrb = sB;
    for (int t = 0; t < T_; ++t) {
        float dot = red[t & 1][0] + red[t & 1][1];
        float a0 = 0.f, a1 = 0.f, a2 = 0.f, a3 = 0.f;
        if (j < H_) {
#pragma unroll
            for (int kk = 0; kk < 25; ++kk) {
                float4 s4 = *(const float4*)&rd[kk * 4];   // broadcast
                a0 = fmaf(Wt[kk].x, s4.x, a0); a1 = fmaf(Wt[kk].y, s4.y, a1);
                a2 = fmaf(Wt[kk].z, s4.z, a2); a3 = fmaf(Wt[kk].w, s4.w, a3);
            }
        }
        // prefetch next step's inputs (stay in flight across the barrier)
        float ntiv = 0.f, nzt = 0.f, nlt = 0.f;
        if (t + 1 < T_) {
            if (j < H_) ntiv = ti[(rb + t + 1) * H_ + j];
            nzt = zr[rb + t + 1]; nlt = lgr[rb + t + 1];
        }
        float part = 0.0f;
        if (j < H_) {
            float sv = (a0 + a1) + (a2 + a3);
            float gate = 1.0f / (1.0f + expf(-(lt + dot + blg)));
            float ns = tanhf(tiv + gate * sv + bts);
            float snew = (1.0f - zt) * sown + zt * ns;
            sown = snew;
            wrb[j] = snew;
            part = wlj * snew;   // partial of NEXT step's gate dot
        }
        tiv = ntiv; zt = nzt; lt = nlt;
#pragma unroll
        for (int off = 1; off < 64; off <<= 1) part += __shfl_xor(part, off, 64);
        if ((j & 63) == 0) red[(t + 1) & 1][wave] = part;
        ldsbar();
        float* tmp = rd; rd = wrb; wrb = tmp;
    }

    if (j < NC_) {
        float o = b_out[j];
        for (int k = 0; k < H_; ++k) o = fmaf(rd[k], W_out[j * H_ + k], o);
        out[b * NC_ + j] = o;
    }
}

// ---------------------------------------------------------------------------
extern "C" void kernel_launch(void* const* d_in, const int* in_sizes, int n_in,
                              void* d_out, int out_size, void* d_ws, size_t ws_size,
                              hipStream_t stream) {
    const int*   txt   = (const int*)d_in[0];
    const int*   lens  = (const int*)d_in[1];
    const float* emb   = (const float*)d_in[2];
    const float* W_ih  = (const float*)d_in[3];
    const float* W_hh  = (const float*)d_in[4];
    const float* b_ih  = (const float*)d_in[5];
    const float* b_hh  = (const float*)d_in[6];
    const float* W_lgr = (const float*)d_in[7];
    const float* b_lgr = (const float*)d_in[8];
    const float* W_ts  = (const float*)d_in[9];
    const float* b_ts  = (const float*)d_in[10];
    const float* W_ti  = (const float*)d_in[11];
    const float* b_ti  = (const float*)d_in[12];
    const float* W_out = (const float*)d_in[13];
    const float* b_out = (const float*)d_in[14];

    float* ws   = (float*)d_ws;
    float* xp   = ws;                    // 39,321,600 floats (157 MB)
    float* rnn  = xp + 39321600;         // 13,107,200 floats (52 MB)
    float* lgrv = rnn + 13107200;        // 131,072
    float* zrv  = lgrv + 131072;         // 131,072
    float* wT   = zrv + 131072;          // 60,000
    float* wcat = wT + 60000;            // 10,400
    float* ti   = xp;                    // reuse xp region after GRU

    float* out = (float*)d_out;

    k_pack<<<276, 256, 0, stream>>>(W_ih, W_ti, W_lgr, wT, wcat);
    k_embgemm<<<4096, 320, 0, stream>>>(txt, emb, wT, b_ih, xp);
    k_gru<<<256, 320, 0, stream>>>(xp, W_hh, b_hh, rnn);
    k_post<<<2048, 256, 0, stream>>>(rnn, wcat, b_ti, lens, ti, lgrv, zrv);
    k_rec<<<256, 128, 0, stream>>>(ti, lgrv, zrv, W_ts, b_ts, W_lgr, b_lgr,
                                   W_out, b_out, out);
}

// Round 6
// 1950.596 us; speedup vs baseline: 1.2396x; 1.0102x over previous
//
#include <hip/hip_runtime.h>

// Problem constants
#define B_   256
#define T_   512
#define E_   200
#define H_   100
#define H3_  300
#define NC_  5

__device__ __forceinline__ void fma4(float4& acc, float a, const float4& w) {
    acc.x = fmaf(a, w.x, acc.x);
    acc.y = fmaf(a, w.y, acc.y);
    acc.z = fmaf(a, w.z, acc.z);
    acc.w = fmaf(a, w.w, acc.w);
}

// Keep a float4 opaque & register-resident: the compiler cannot rematerialize
// or re-sink the load that produced it (round-5 post-mortem: VGPR_Count=88
// proved W_hh loads were being re-issued every scan step from L1/L2).
#define KEEP4(v) asm volatile("" : "+v"((v).x), "+v"((v).y), "+v"((v).z), "+v"((v).w))

// Light barrier: drain LDS ops only (NOT global/vmcnt), then raw s_barrier.
// __syncthreads() would emit s_waitcnt vmcnt(0) and put HBM store/prefetch
// latency on the scan critical path every step.
__device__ __forceinline__ void ldsbar() {
    asm volatile("s_waitcnt lgkmcnt(0)" ::: "memory");
    __builtin_amdgcn_s_barrier();
    __builtin_amdgcn_sched_barrier(0);
}

// ---------------------------------------------------------------------------
// T0: pack weights: W_ihT[k][j] = W_ih[j][k]  (200x300)
//     wcat[k][j]: j<100 -> W_ti[j][k]; j==100 -> W_lgr[0][k]; else 0  (100x104)
// ---------------------------------------------------------------------------
__global__ void k_pack(const float* __restrict__ W_ih, const float* __restrict__ W_ti,
                       const float* __restrict__ W_lgr,
                       float* __restrict__ wT, float* __restrict__ wcat) {
    int idx = blockIdx.x * 256 + threadIdx.x;
    if (idx < E_ * H3_) {
        int k = idx / H3_, j = idx - k * H3_;
        wT[idx] = W_ih[j * E_ + k];
    }
    int i2 = idx - E_ * H3_;
    if (i2 >= 0 && i2 < H_ * 104) {
        int k = i2 / 104, j = i2 - k * 104;
        float v = 0.0f;
        if (j < H_) v = W_ti[j * H_ + k];
        else if (j == H_) v = W_lgr[k];
        wcat[i2] = v;
    }
}

// ---------------------------------------------------------------------------
// A: xp[row][j] = scale(row) * dot(emb[txt[row]], W_ih[j]) + b_ih[j]
// ---------------------------------------------------------------------------
__global__ __launch_bounds__(320) void k_embgemm(
        const int* __restrict__ txt, const float* __restrict__ emb,
        const float* __restrict__ wT, const float* __restrict__ b_ih,
        float* __restrict__ xp) {
    __shared__ __align__(16) float A_lds[E_ * 36];   // [k][r], stride 36 (28.8 KB)
    __shared__ __align__(16) float W_lds[32 * 320];  // [kk][j], stride 320 (40 KB)
    __shared__ float scale_lds[32];

    int tid = threadIdx.x;
    int base = blockIdx.x * 32;

    for (int idx = tid; idx < 32 * E_; idx += 320) {
        int r = idx / E_, k = idx - r * E_;
        int row = txt[base + r];
        A_lds[k * 36 + r] = emb[(size_t)row * E_ + k];
    }
    __syncthreads();

    if (tid < 32) {
        float ss = 0.0f;
        for (int k = 0; k < E_; ++k) { float v = A_lds[k * 36 + tid]; ss = fmaf(v, v, ss); }
        float n = sqrtf(ss);
        scale_lds[tid] = (n > 1.0f) ? (1.0f / (n + 1e-7f)) : 1.0f;
    }

    int c = tid % 80, g = tid / 80;
    float4 acc[8];
#pragma unroll
    for (int i = 0; i < 8; ++i) acc[i] = make_float4(0.f, 0.f, 0.f, 0.f);

    for (int kc = 0; kc < E_; kc += 32) {
        int KC = min(32, E_ - kc);
        __syncthreads();
        for (int idx = tid; idx < KC * H3_; idx += 320) {
            int kk = idx / H3_, j = idx - kk * H3_;
            W_lds[kk * 320 + j] = wT[(kc + kk) * H3_ + j];
        }
        __syncthreads();
        if (c < 75) {
            for (int kk = 0; kk < KC; ++kk) {
                int k = kc + kk;
                float4 wv = *(const float4*)&W_lds[kk * 320 + c * 4];
                float4 a0 = *(const float4*)&A_lds[k * 36 + g * 8];
                float4 a1 = *(const float4*)&A_lds[k * 36 + g * 8 + 4];
                fma4(acc[0], a0.x, wv); fma4(acc[1], a0.y, wv);
                fma4(acc[2], a0.z, wv); fma4(acc[3], a0.w, wv);
                fma4(acc[4], a1.x, wv); fma4(acc[5], a1.y, wv);
                fma4(acc[6], a1.z, wv); fma4(acc[7], a1.w, wv);
            }
        }
    }

    if (c < 75) {
        float4 bv = *(const float4*)&b_ih[c * 4];
#pragma unroll
        for (int rr = 0; rr < 8; ++rr) {
            int r = g * 8 + rr;
            float s = scale_lds[r];
            float4 res;
            res.x = fmaf(acc[rr].x, s, bv.x);
            res.y = fmaf(acc[rr].y, s, bv.y);
            res.z = fmaf(acc[rr].z, s, bv.z);
            res.w = fmaf(acc[rr].w, s, bv.w);
            *(float4*)&xp[(size_t)(base + r) * H3_ + c * 4] = res;
        }
    }
}

// ---------------------------------------------------------------------------
// B: GRU scan. 1 block per batch row, 320 threads (5 waves).
// Thread j<300 holds ONE W_hh row (100 floats) in VGPRs, pinned via KEEP4 +
// amdgpu_waves_per_eu(1,2) (grid = 1 block/CU, so capping occupancy is free).
// Two LIGHT barriers per step (lgkmcnt-only): rnn store and x prefetch stay
// in flight across barriers, waited only at use one step later.
// ---------------------------------------------------------------------------
__global__ __launch_bounds__(320)
__attribute__((amdgpu_waves_per_eu(1, 2)))
void k_gru(
        const float* __restrict__ xp, const float* __restrict__ W_hh,
        const float* __restrict__ b_hh, float* __restrict__ rnn) {
    __shared__ __align__(16) float h_lds[104];
    __shared__ float hp_lds[H3_];

    int j = threadIdx.x;
    int b = blockIdx.x;

    float4 W4[25];
    float bh = 0.0f;
    if (j < H3_) {
        const float4* wr = (const float4*)(W_hh + (size_t)j * H_);
#pragma unroll
        for (int kk = 0; kk < 25; ++kk) W4[kk] = wr[kk];
#pragma unroll
        for (int kk = 0; kk < 25; ++kk) KEEP4(W4[kk]);
        bh = b_hh[j];
    }
    if (j < 104) h_lds[j] = 0.0f;
    float hown = 0.0f;  // thread j<100 keeps its own h[j]

    const float* xpb = xp + (size_t)b * T_ * H3_;
    float* rnnb = rnn + (size_t)b * T_ * H_;
    float xr = 0.f, xz = 0.f, xn = 0.f;
    if (j < H_) { xr = xpb[j]; xz = xpb[H_ + j]; xn = xpb[2 * H_ + j]; }
    __syncthreads();

    for (int t = 0; t < T_; ++t) {
        float acc0 = bh, acc1 = 0.f, acc2 = 0.f, acc3 = 0.f;
        if (j < H3_) {
#pragma unroll
            for (int kk = 0; kk < 25; ++kk) {
                float4 hv = *(const float4*)&h_lds[kk * 4];  // broadcast read
                acc0 = fmaf(W4[kk].x, hv.x, acc0);
                acc1 = fmaf(W4[kk].y, hv.y, acc1);
                acc2 = fmaf(W4[kk].z, hv.z, acc2);
                acc3 = fmaf(W4[kk].w, hv.w, acc3);
            }
            hp_lds[j] = (acc0 + acc1) + (acc2 + acc3);
        }
        // prefetch next step's x while matvec/barrier are in flight
        float nxr = 0.f, nxz = 0.f, nxn = 0.f;
        if (j < H_ && t + 1 < T_) {
            const float* xq = xpb + (size_t)(t + 1) * H3_;
            nxr = xq[j]; nxz = xq[H_ + j]; nxn = xq[2 * H_ + j];
        }
        ldsbar();  // hp visible
        if (j < H_) {
            float hr = hp_lds[j], hz = hp_lds[H_ + j], hn = hp_lds[2 * H_ + j];
            float r = 1.0f / (1.0f + expf(-(xr + hr)));
            float z = 1.0f / (1.0f + expf(-(xz + hz)));
            float ng = tanhf(xn + r * hn);
            float hnew = (1.0f - z) * ng + z * hown;
            hown = hnew;
            h_lds[j] = hnew;
            rnnb[(size_t)t * H_ + j] = hnew;   // fire-and-forget (not drained)
            xr = nxr; xz = nxz; xn = nxn;
        }
        ldsbar();  // h visible for next matvec
    }
}

// ---------------------------------------------------------------------------
// C: ti = rnn @ W_ti.T + b_ti ; lgr = rnn @ W_lgr[:, :H].T ; z = relu(att*mask)
// ---------------------------------------------------------------------------
__global__ __launch_bounds__(256) void k_post(
        const float* __restrict__ rnn, const float* __restrict__ wcat,
        const float* __restrict__ b_ti, const int* __restrict__ lens,
        float* __restrict__ ti, float* __restrict__ lgr, float* __restrict__ zr) {
    __shared__ __align__(16) float A_lds[H_ * 72];   // [k][r], stride 72 (28.8 KB)
    __shared__ __align__(16) float W_lds[H_ * 112];  // [k][j], stride 112 (44.8 KB)

    int tid = threadIdx.x;
    int base = blockIdx.x * 64;

    for (int idx = tid; idx < 64 * H_; idx += 256) {
        int r = idx / H_, k = idx - r * H_;
        A_lds[k * 72 + r] = rnn[(size_t)(base + r) * H_ + k];
    }
    for (int idx = tid; idx < H_ * 104; idx += 256) {
        int k = idx / 104, jj = idx - k * 104;
        W_lds[k * 112 + jj] = wcat[idx];
    }
    __syncthreads();

    if (tid < 64) {
        float ss = 0.f, sm = 0.f;
        for (int k = 0; k < H_; ++k) {
            float v = A_lds[k * 72 + tid];
            ss = fmaf(v, v, ss); sm += v;
        }
        int row = base + tid;
        int bb = row >> 9, tt = row & 511;
        float att = sm / (fmaxf(sqrtf(ss), 1e-12f) * 1000.0f);  // / (norm * sqrt(H) * H)
        zr[row] = (tt < lens[bb]) ? fmaxf(att, 0.0f) : 0.0f;
    }

    int c = tid % 32, g = tid / 32;
    float4 acc[8];
#pragma unroll
    for (int i = 0; i < 8; ++i) acc[i] = make_float4(0.f, 0.f, 0.f, 0.f);

    if (c < 26) {
        for (int k = 0; k < H_; ++k) {
            float4 wv = *(const float4*)&W_lds[k * 112 + c * 4];
            float4 a0 = *(const float4*)&A_lds[k * 72 + g * 8];
            float4 a1 = *(const float4*)&A_lds[k * 72 + g * 8 + 4];
            fma4(acc[0], a0.x, wv); fma4(acc[1], a0.y, wv);
            fma4(acc[2], a0.z, wv); fma4(acc[3], a0.w, wv);
            fma4(acc[4], a1.x, wv); fma4(acc[5], a1.y, wv);
            fma4(acc[6], a1.z, wv); fma4(acc[7], a1.w, wv);
        }
    }

    if (c < 25) {
        float4 bv = *(const float4*)&b_ti[c * 4];
#pragma unroll
        for (int rr = 0; rr < 8; ++rr) {
            int row = base + g * 8 + rr;
            float4 res;
            res.x = acc[rr].x + bv.x; res.y = acc[rr].y + bv.y;
            res.z = acc[rr].z + bv.z; res.w = acc[rr].w + bv.w;
            *(float4*)&ti[(size_t)row * H_ + c * 4] = res;
        }
    } else if (c == 25) {
#pragma unroll
        for (int rr = 0; rr < 8; ++rr) {
            int row = base + g * 8 + rr;
            lgr[row] = acc[rr].x;  // j == 100 column
        }
    }
}

// ---------------------------------------------------------------------------
// D: rec scan + final GEMV. 1 block per batch row, 128 threads (2 waves).
// Thread j<100 holds W_ts row j (100 floats, KEEP4-pinned) + wl_j in VGPRs.
// Gate dot wl·s PIPELINED via shfl_xor tree + parity-double-buffered red[],
// merged into the single light barrier.
// ---------------------------------------------------------------------------
__global__ __launch_bounds__(128)
__attribute__((amdgpu_waves_per_eu(1, 1)))
void k_rec(
        const float* __restrict__ ti, const float* __restrict__ lgr,
        const float* __restrict__ zr,
        const float* __restrict__ W_ts, const float* __restrict__ b_ts,
        const float* __restrict__ W_lgr, const float* __restrict__ b_lgr,
        const float* __restrict__ W_out, const float* __restrict__ b_out,
        float* __restrict__ out) {
    __shared__ __align__(16) float sA[104];
    __shared__ __align__(16) float sB[104];
    __shared__ float red[2][2];   // [parity][wave]

    int j = threadIdx.x;
    int b = blockIdx.x;
    int wave = j >> 6;

    float4 Wt[25];
    float bts = 0.f, wlj = 0.f;
    if (j < H_) {
        const float4* wr = (const float4*)(W_ts + (size_t)j * H_);
#pragma unroll
        for (int kk = 0; kk < 25; ++kk) Wt[kk] = wr[kk];
#pragma unroll
        for (int kk = 0; kk < 25; ++kk) KEEP4(Wt[kk]);
        bts = b_ts[j];
        wlj = W_lgr[H_ + j];
    }
    if (j < 104) { sA[j] = 0.0f; }
    if (j < 4) ((float*)red)[j] = 0.0f;
    float blg = b_lgr[0];
    float sown = 0.0f;

    size_t rb = (size_t)b * T_;
    float tiv = 0.f, zt = 0.f, lt = 0.f;
    if (j < H_) tiv = ti[rb * H_ + j];
    zt = zr[rb]; lt = lgr[rb];
    __syncthreads();

    float* rd = sA;
    float* wrb = sB;
    for (int t = 0; t < T_; ++t) {
        float dot = red[t & 1][0] + red[t & 1][1];
        float a0 = 0.f, a1 = 0.f, a2 = 0.f, a3 = 0.f;
        if (j < H_) {
#pragma unroll
            for (int kk = 0; kk < 25; ++kk) {
                float4 s4 = *(const float4*)&rd[kk * 4];   // broadcast
                a0 = fmaf(Wt[kk].x, s4.x, a0); a1 = fmaf(Wt[kk].y, s4.y, a1);
                a2 = fmaf(Wt[kk].z, s4.z, a2); a3 = fmaf(Wt[kk].w, s4.w, a3);
            }
        }
        // prefetch next step's inputs (stay in flight across the barrier)
        float ntiv = 0.f, nzt = 0.f, nlt = 0.f;
        if (t + 1 < T_) {
            if (j < H_) ntiv = ti[(rb + t + 1) * H_ + j];
            nzt = zr[rb + t + 1]; nlt = lgr[rb + t + 1];
        }
        float part = 0.0f;
        if (j < H_) {
            float sv = (a0 + a1) + (a2 + a3);
            float gate = 1.0f / (1.0f + expf(-(lt + dot + blg)));
            float ns = tanhf(tiv + gate * sv + bts);
            float snew = (1.0f - zt) * sown + zt * ns;
            sown = snew;
            wrb[j] = snew;
            part = wlj * snew;   // partial of NEXT step's gate dot
        }
        tiv = ntiv; zt = nzt; lt = nlt;
#pragma unroll
        for (int off = 1; off < 64; off <<= 1) part += __shfl_xor(part, off, 64);
        if ((j & 63) == 0) red[(t + 1) & 1][wave] = part;
        ldsbar();
        float* tmp = rd; rd = wrb; wrb = tmp;
    }

    if (j < NC_) {
        float o = b_out[j];
        for (int k = 0; k < H_; ++k) o = fmaf(rd[k], W_out[j * H_ + k], o);
        out[b * NC_ + j] = o;
    }
}

// ---------------------------------------------------------------------------
extern "C" void kernel_launch(void* const* d_in, const int* in_sizes, int n_in,
                              void* d_out, int out_size, void* d_ws, size_t ws_size,
                              hipStream_t stream) {
    const int*   txt   = (const int*)d_in[0];
    const int*   lens  = (const int*)d_in[1];
    const float* emb   = (const float*)d_in[2];
    const float* W_ih  = (const float*)d_in[3];
    const float* W_hh  = (const float*)d_in[4];
    const float* b_ih  = (const float*)d_in[5];
    const float* b_hh  = (const float*)d_in[6];
    const float* W_lgr = (const float*)d_in[7];
    const float* b_lgr = (const float*)d_in[8];
    const float* W_ts  = (const float*)d_in[9];
    const float* b_ts  = (const float*)d_in[10];
    const float* W_ti  = (const float*)d_in[11];
    const float* b_ti  = (const float*)d_in[12];
    const float* W_out = (const float*)d_in[13];
    const float* b_out = (const float*)d_in[14];

    float* ws   = (float*)d_ws;
    float* xp   = ws;                    // 39,321,600 floats (157 MB)
    float* rnn  = xp + 39321600;         // 13,107,200 floats (52 MB)
    float* lgrv = rnn + 13107200;        // 131,072
    float* zrv  = lgrv + 131072;         // 131,072
    float* wT   = zrv + 131072;          // 60,000
    float* wcat = wT + 60000;            // 10,400
    float* ti   = xp;                    // reuse xp region after GRU

    float* out = (float*)d_out;

    k_pack<<<276, 256, 0, stream>>>(W_ih, W_ti, W_lgr, wT, wcat);
    k_embgemm<<<4096, 320, 0, stream>>>(txt, emb, wT, b_ih, xp);
    k_gru<<<256, 320, 0, stream>>>(xp, W_hh, b_hh, rnn);
    k_post<<<2048, 256, 0, stream>>>(rnn, wcat, b_ti, lens, ti, lgrv, zrv);
    k_rec<<<256, 128, 0, stream>>>(ti, lgrv, zrv, W_ts, b_ts, W_lgr, b_lgr,
                                   W_out, b_out, out);
}

// Round 7
// 1681.703 us; speedup vs baseline: 1.4378x; 1.1599x over previous
//
#include <hip/hip_runtime.h>

// Problem constants
#define B_   256
#define T_   512
#define E_   200
#define H_   100
#define H3_  300
#define NC_  5

__device__ __forceinline__ void fma4(float4& acc, float a, const float4& w) {
    acc.x = fmaf(a, w.x, acc.x);
    acc.y = fmaf(a, w.y, acc.y);
    acc.z = fmaf(a, w.z, acc.z);
    acc.w = fmaf(a, w.w, acc.w);
}

// Pin a float4 into registers (blocks remat/re-sinking of the producing load).
#define KEEP4(v) asm volatile("" : "+v"((v).x), "+v"((v).y), "+v"((v).z), "+v"((v).w))

// Light barrier: drain LDS ops only (NOT global/vmcnt), then raw s_barrier.
// __syncthreads() would emit s_waitcnt vmcnt(0) and put HBM store/prefetch
// latency on the scan critical path every step.
__device__ __forceinline__ void ldsbar() {
    asm volatile("s_waitcnt lgkmcnt(0)" ::: "memory");
    __builtin_amdgcn_s_barrier();
    __builtin_amdgcn_sched_barrier(0);
}

// ---------------------------------------------------------------------------
// T0: pack weights: W_ihT[k][j] = W_ih[j][k]  (200x300)
//     wcat[k][j]: j<100 -> W_ti[j][k]; j==100 -> W_lgr[0][k]; else 0  (100x104)
// ---------------------------------------------------------------------------
__global__ void k_pack(const float* __restrict__ W_ih, const float* __restrict__ W_ti,
                       const float* __restrict__ W_lgr,
                       float* __restrict__ wT, float* __restrict__ wcat) {
    int idx = blockIdx.x * 256 + threadIdx.x;
    if (idx < E_ * H3_) {
        int k = idx / H3_, j = idx - k * H3_;
        wT[idx] = W_ih[j * E_ + k];
    }
    int i2 = idx - E_ * H3_;
    if (i2 >= 0 && i2 < H_ * 104) {
        int k = i2 / 104, j = i2 - k * 104;
        float v = 0.0f;
        if (j < H_) v = W_ti[j * H_ + k];
        else if (j == H_) v = W_lgr[k];
        wcat[i2] = v;
    }
}

// ---------------------------------------------------------------------------
// A: xp[row][j] = scale(row) * dot(emb[txt[row]], W_ih[j]) + b_ih[j]
// ---------------------------------------------------------------------------
__global__ __launch_bounds__(320) void k_embgemm(
        const int* __restrict__ txt, const float* __restrict__ emb,
        const float* __restrict__ wT, const float* __restrict__ b_ih,
        float* __restrict__ xp) {
    __shared__ __align__(16) float A_lds[E_ * 36];   // [k][r], stride 36 (28.8 KB)
    __shared__ __align__(16) float W_lds[32 * 320];  // [kk][j], stride 320 (40 KB)
    __shared__ float scale_lds[32];

    int tid = threadIdx.x;
    int base = blockIdx.x * 32;

    for (int idx = tid; idx < 32 * E_; idx += 320) {
        int r = idx / E_, k = idx - r * E_;
        int row = txt[base + r];
        A_lds[k * 36 + r] = emb[(size_t)row * E_ + k];
    }
    __syncthreads();

    if (tid < 32) {
        float ss = 0.0f;
        for (int k = 0; k < E_; ++k) { float v = A_lds[k * 36 + tid]; ss = fmaf(v, v, ss); }
        float n = sqrtf(ss);
        scale_lds[tid] = (n > 1.0f) ? (1.0f / (n + 1e-7f)) : 1.0f;
    }

    int c = tid % 80, g = tid / 80;
    float4 acc[8];
#pragma unroll
    for (int i = 0; i < 8; ++i) acc[i] = make_float4(0.f, 0.f, 0.f, 0.f);

    for (int kc = 0; kc < E_; kc += 32) {
        int KC = min(32, E_ - kc);
        __syncthreads();
        for (int idx = tid; idx < KC * H3_; idx += 320) {
            int kk = idx / H3_, j = idx - kk * H3_;
            W_lds[kk * 320 + j] = wT[(kc + kk) * H3_ + j];
        }
        __syncthreads();
        if (c < 75) {
            for (int kk = 0; kk < KC; ++kk) {
                int k = kc + kk;
                float4 wv = *(const float4*)&W_lds[kk * 320 + c * 4];
                float4 a0 = *(const float4*)&A_lds[k * 36 + g * 8];
                float4 a1 = *(const float4*)&A_lds[k * 36 + g * 8 + 4];
                fma4(acc[0], a0.x, wv); fma4(acc[1], a0.y, wv);
                fma4(acc[2], a0.z, wv); fma4(acc[3], a0.w, wv);
                fma4(acc[4], a1.x, wv); fma4(acc[5], a1.y, wv);
                fma4(acc[6], a1.z, wv); fma4(acc[7], a1.w, wv);
            }
        }
    }

    if (c < 75) {
        float4 bv = *(const float4*)&b_ih[c * 4];
#pragma unroll
        for (int rr = 0; rr < 8; ++rr) {
            int r = g * 8 + rr;
            float s = scale_lds[r];
            float4 res;
            res.x = fmaf(acc[rr].x, s, bv.x);
            res.y = fmaf(acc[rr].y, s, bv.y);
            res.z = fmaf(acc[rr].z, s, bv.z);
            res.w = fmaf(acc[rr].w, s, bv.w);
            *(float4*)&xp[(size_t)(base + r) * H3_ + c * 4] = res;
        }
    }
}

// ---------------------------------------------------------------------------
// B: GRU scan. 1 block per batch row, 640 threads (10 waves).
// SPLIT-ROW weights: thread (half,j) holds HALF of W_hh row j (13 float4,
// ~52 regs -> no spill possible). half0: k 0..51; half1: k 48..99 with w[0]
// zeroed (k 48..51 counted by half0). Partials combined via p_lds; gate
// thread j<100 reuses its own half0 partial from register.
// Two light barriers/step; rnn store + x prefetch stay in flight.
// ---------------------------------------------------------------------------
__global__ __launch_bounds__(640, 3)
void k_gru(
        const float* __restrict__ xp, const float* __restrict__ W_hh,
        const float* __restrict__ b_hh, float* __restrict__ rnn) {
    __shared__ __align__(16) float h_lds[104];
    __shared__ float p_lds[640];

    int tid = threadIdx.x;
    int half = (tid >= 320) ? 1 : 0;
    int j = tid - half * 320;          // row 0..319 (<300 active)
    int kb = half ? 48 : 0;
    int b = blockIdx.x;

    float4 w[13];
    if (j < H3_) {
        const float4* wr = (const float4*)(W_hh + (size_t)j * H_ + kb);
#pragma unroll
        for (int i = 0; i < 13; ++i) w[i] = wr[i];
        if (half) w[0] = make_float4(0.f, 0.f, 0.f, 0.f);
#pragma unroll
        for (int i = 0; i < 13; ++i) KEEP4(w[i]);
    } else {
#pragma unroll
        for (int i = 0; i < 13; ++i) w[i] = make_float4(0.f, 0.f, 0.f, 0.f);
    }

    float bhr = 0.f, bhz = 0.f, bhn = 0.f;
    if (tid < H_) { bhr = b_hh[tid]; bhz = b_hh[H_ + tid]; bhn = b_hh[2 * H_ + tid]; }

    if (tid < 104) h_lds[tid] = 0.0f;
    float hown = 0.0f;  // thread tid<100 keeps its own h[tid]

    const float* xpb = xp + (size_t)b * T_ * H3_;
    float* rnnb = rnn + (size_t)b * T_ * H_;
    float xr = 0.f, xz = 0.f, xn = 0.f;
    if (tid < H_) { xr = xpb[tid]; xz = xpb[H_ + tid]; xn = xpb[2 * H_ + tid]; }
    __syncthreads();

    for (int t = 0; t < T_; ++t) {
        float a0 = 0.f, a1 = 0.f, a2 = 0.f, a3 = 0.f;
#pragma unroll
        for (int i = 0; i < 13; ++i) {
            float4 hv = *(const float4*)&h_lds[kb + i * 4];  // broadcast read
            a0 = fmaf(w[i].x, hv.x, a0);
            a1 = fmaf(w[i].y, hv.y, a1);
            a2 = fmaf(w[i].z, hv.z, a2);
            a3 = fmaf(w[i].w, hv.w, a3);
        }
        float ownp = (a0 + a1) + (a2 + a3);
        if (j < H3_) p_lds[tid] = ownp;
        // prefetch next step's x (stays in flight across the barrier)
        float nxr = 0.f, nxz = 0.f, nxn = 0.f;
        if (tid < H_ && t + 1 < T_) {
            const float* xq = xpb + (size_t)(t + 1) * H3_;
            nxr = xq[tid]; nxz = xq[H_ + tid]; nxn = xq[2 * H_ + tid];
        }
        ldsbar();  // partials visible
        if (tid < H_) {
            float hr = ownp             + p_lds[320 + tid] + bhr;  // own row's half0
            float hz = p_lds[100 + tid] + p_lds[420 + tid] + bhz;
            float hn = p_lds[200 + tid] + p_lds[520 + tid] + bhn;
            float r = 1.0f / (1.0f + expf(-(xr + hr)));
            float z = 1.0f / (1.0f + expf(-(xz + hz)));
            float ng = tanhf(xn + r * hn);
            float hnew = (1.0f - z) * ng + z * hown;
            hown = hnew;
            h_lds[tid] = hnew;
            rnnb[(size_t)t * H_ + tid] = hnew;   // fire-and-forget
            xr = nxr; xz = nxz; xn = nxn;
        }
        ldsbar();  // h visible for next matvec
    }
}

// ---------------------------------------------------------------------------
// C: ti = rnn @ W_ti.T + b_ti ; lgr = rnn @ W_lgr[:, :H].T ; z = relu(att*mask)
// ---------------------------------------------------------------------------
__global__ __launch_bounds__(256) void k_post(
        const float* __restrict__ rnn, const float* __restrict__ wcat,
        const float* __restrict__ b_ti, const int* __restrict__ lens,
        float* __restrict__ ti, float* __restrict__ lgr, float* __restrict__ zr) {
    __shared__ __align__(16) float A_lds[H_ * 72];   // [k][r], stride 72 (28.8 KB)
    __shared__ __align__(16) float W_lds[H_ * 112];  // [k][j], stride 112 (44.8 KB)

    int tid = threadIdx.x;
    int base = blockIdx.x * 64;

    for (int idx = tid; idx < 64 * H_; idx += 256) {
        int r = idx / H_, k = idx - r * H_;
        A_lds[k * 72 + r] = rnn[(size_t)(base + r) * H_ + k];
    }
    for (int idx = tid; idx < H_ * 104; idx += 256) {
        int k = idx / 104, jj = idx - k * 104;
        W_lds[k * 112 + jj] = wcat[idx];
    }
    __syncthreads();

    if (tid < 64) {
        float ss = 0.f, sm = 0.f;
        for (int k = 0; k < H_; ++k) {
            float v = A_lds[k * 72 + tid];
            ss = fmaf(v, v, ss); sm += v;
        }
        int row = base + tid;
        int bb = row >> 9, tt = row & 511;
        float att = sm / (fmaxf(sqrtf(ss), 1e-12f) * 1000.0f);  // / (norm * sqrt(H) * H)
        zr[row] = (tt < lens[bb]) ? fmaxf(att, 0.0f) : 0.0f;
    }

    int c = tid % 32, g = tid / 32;
    float4 acc[8];
#pragma unroll
    for (int i = 0; i < 8; ++i) acc[i] = make_float4(0.f, 0.f, 0.f, 0.f);

    if (c < 26) {
        for (int k = 0; k < H_; ++k) {
            float4 wv = *(const float4*)&W_lds[k * 112 + c * 4];
            float4 a0 = *(const float4*)&A_lds[k * 72 + g * 8];
            float4 a1 = *(const float4*)&A_lds[k * 72 + g * 8 + 4];
            fma4(acc[0], a0.x, wv); fma4(acc[1], a0.y, wv);
            fma4(acc[2], a0.z, wv); fma4(acc[3], a0.w, wv);
            fma4(acc[4], a1.x, wv); fma4(acc[5], a1.y, wv);
            fma4(acc[6], a1.z, wv); fma4(acc[7], a1.w, wv);
        }
    }

    if (c < 25) {
        float4 bv = *(const float4*)&b_ti[c * 4];
#pragma unroll
        for (int rr = 0; rr < 8; ++rr) {
            int row = base + g * 8 + rr;
            float4 res;
            res.x = acc[rr].x + bv.x; res.y = acc[rr].y + bv.y;
            res.z = acc[rr].z + bv.z; res.w = acc[rr].w + bv.w;
            *(float4*)&ti[(size_t)row * H_ + c * 4] = res;
        }
    } else if (c == 25) {
#pragma unroll
        for (int rr = 0; rr < 8; ++rr) {
            int row = base + g * 8 + rr;
            lgr[row] = acc[rr].x;  // j == 100 column
        }
    }
}

// ---------------------------------------------------------------------------
// D: rec scan + final GEMV. 1 block per batch row, 256 threads (4 waves).
// SPLIT-ROW weights: thread (half,j) holds half of W_ts row j (13 float4).
// Only half1 writes partials to LDS; gate thread j<100 keeps its own half0
// partial in register. Gate dot wl·s pipelined via shfl_xor + parity red[].
// ---------------------------------------------------------------------------
__global__ __launch_bounds__(256, 1)
void k_rec(
        const float* __restrict__ ti, const float* __restrict__ lgr,
        const float* __restrict__ zr,
        const float* __restrict__ W_ts, const float* __restrict__ b_ts,
        const float* __restrict__ W_lgr, const float* __restrict__ b_lgr,
        const float* __restrict__ W_out, const float* __restrict__ b_out,
        float* __restrict__ out) {
    __shared__ __align__(16) float sA[104];
    __shared__ __align__(16) float sB[104];
    __shared__ float p_lds[256];
    __shared__ float red[2][2];   // [parity][wave]

    int tid = threadIdx.x;
    int half = (tid >= 128) ? 1 : 0;
    int j = tid - half * 128;      // row 0..127 (<100 active)
    int kb = half ? 48 : 0;
    int b = blockIdx.x;

    float4 w[13];
    if (j < H_) {
        const float4* wr = (const float4*)(W_ts + (size_t)j * H_ + kb);
#pragma unroll
        for (int i = 0; i < 13; ++i) w[i] = wr[i];
        if (half) w[0] = make_float4(0.f, 0.f, 0.f, 0.f);
#pragma unroll
        for (int i = 0; i < 13; ++i) KEEP4(w[i]);
    } else {
#pragma unroll
        for (int i = 0; i < 13; ++i) w[i] = make_float4(0.f, 0.f, 0.f, 0.f);
    }

    float bts = 0.f, wlj = 0.f;
    if (tid < H_) { bts = b_ts[tid]; wlj = W_lgr[H_ + tid]; }
    float blg = b_lgr[0];
    if (tid < 104) sA[tid] = 0.0f;
    if (tid < 4) ((float*)red)[tid] = 0.0f;
    float sown = 0.0f;

    size_t rb = (size_t)b * T_;
    float tiv = 0.f, zt = 0.f, lt = 0.f;
    if (tid < H_) tiv = ti[rb * H_ + tid];
    zt = zr[rb]; lt = lgr[rb];
    __syncthreads();

    float* rd = sA;
    float* wrb = sB;
    for (int t = 0; t < T_; ++t) {
        float a0 = 0.f, a1 = 0.f, a2 = 0.f, a3 = 0.f;
#pragma unroll
        for (int i = 0; i < 13; ++i) {
            float4 s4 = *(const float4*)&rd[kb + i * 4];   // broadcast
            a0 = fmaf(w[i].x, s4.x, a0); a1 = fmaf(w[i].y, s4.y, a1);
            a2 = fmaf(w[i].z, s4.z, a2); a3 = fmaf(w[i].w, s4.w, a3);
        }
        float ownp = (a0 + a1) + (a2 + a3);
        if (half && j < H_) p_lds[tid] = ownp;
        // prefetch next step's inputs (stay in flight across the barrier)
        float ntiv = 0.f, nzt = 0.f, nlt = 0.f;
        if (t + 1 < T_) {
            if (tid < H_) ntiv = ti[(rb + t + 1) * H_ + tid];
            nzt = zr[rb + t + 1]; nlt = lgr[rb + t + 1];
        }
        ldsbar();  // half1 partials visible
        float dot = red[t & 1][0] + red[t & 1][1];
        float part = 0.0f;
        if (tid < H_) {
            float sv = ownp + p_lds[128 + tid];
            float gate = 1.0f / (1.0f + expf(-(lt + dot + blg)));
            float ns = tanhf(tiv + gate * sv + bts);
            float snew = (1.0f - zt) * sown + zt * ns;
            sown = snew;
            wrb[tid] = snew;
            part = wlj * snew;   // partial of NEXT step's gate dot
        }
        tiv = ntiv; zt = nzt; lt = nlt;
#pragma unroll
        for (int off = 1; off < 64; off <<= 1) part += __shfl_xor(part, off, 64);
        if ((tid & 63) == 0 && tid < 128) red[(t + 1) & 1][tid >> 6] = part;
        ldsbar();  // state + red visible
        float* tmp = rd; rd = wrb; wrb = tmp;
    }

    if (tid < NC_) {
        float o = b_out[tid];
        for (int k = 0; k < H_; ++k) o = fmaf(rd[k], W_out[tid * H_ + k], o);
        out[b * NC_ + tid] = o;
    }
}

// ---------------------------------------------------------------------------
extern "C" void kernel_launch(void* const* d_in, const int* in_sizes, int n_in,
                              void* d_out, int out_size, void* d_ws, size_t ws_size,
                              hipStream_t stream) {
    const int*   txt   = (const int*)d_in[0];
    const int*   lens  = (const int*)d_in[1];
    const float* emb   = (const float*)d_in[2];
    const float* W_ih  = (const float*)d_in[3];
    const float* W_hh  = (const float*)d_in[4];
    const float* b_ih  = (const float*)d_in[5];
    const float* b_hh  = (const float*)d_in[6];
    const float* W_lgr = (const float*)d_in[7];
    const float* b_lgr = (const float*)d_in[8];
    const float* W_ts  = (const float*)d_in[9];
    const float* b_ts  = (const float*)d_in[10];
    const float* W_ti  = (const float*)d_in[11];
    const float* b_ti  = (const float*)d_in[12];
    const float* W_out = (const float*)d_in[13];
    const float* b_out = (const float*)d_in[14];

    float* ws   = (float*)d_ws;
    float* xp   = ws;                    // 39,321,600 floats (157 MB)
    float* rnn  = xp + 39321600;         // 13,107,200 floats (52 MB)
    float* lgrv = rnn + 13107200;        // 131,072
    float* zrv  = lgrv + 131072;         // 131,072
    float* wT   = zrv + 131072;          // 60,000
    float* wcat = wT + 60000;            // 10,400
    float* ti   = xp;                    // reuse xp region after GRU

    float* out = (float*)d_out;

    k_pack<<<276, 256, 0, stream>>>(W_ih, W_ti, W_lgr, wT, wcat);
    k_embgemm<<<4096, 320, 0, stream>>>(txt, emb, wT, b_ih, xp);
    k_gru<<<256, 640, 0, stream>>>(xp, W_hh, b_hh, rnn);
    k_post<<<2048, 256, 0, stream>>>(rnn, wcat, b_ti, lens, ti, lgrv, zrv);
    k_rec<<<256, 256, 0, stream>>>(ti, lgrv, zrv, W_ts, b_ts, W_lgr, b_lgr,
                                   W_out, b_out, out);
}

// Round 8
// 1528.019 us; speedup vs baseline: 1.5824x; 1.1006x over previous
//
#include <hip/hip_runtime.h>

// Problem constants
#define B_   256
#define T_   512
#define E_   200
#define H_   100
#define H3_  300
#define NC_  5

#define WSTRIDE 304   // W_lds row stride in floats (16B-aligned, breaks pow2)

__device__ __forceinline__ void fma4(float4& acc, float a, const float4& w) {
    acc.x = fmaf(a, w.x, acc.x);
    acc.y = fmaf(a, w.y, acc.y);
    acc.z = fmaf(a, w.z, acc.z);
    acc.w = fmaf(a, w.w, acc.w);
}

// Pin a float4 into registers (blocks remat/re-sinking of the producing load).
#define KEEP4(v) asm volatile("" : "+v"((v).x), "+v"((v).y), "+v"((v).z), "+v"((v).w))

// Light barrier: drain LDS ops only (NOT global/vmcnt), then raw s_barrier.
// __syncthreads() would emit s_waitcnt vmcnt(0) and put HBM/L2 load latency
// on the critical path.
__device__ __forceinline__ void ldsbar() {
    asm volatile("s_waitcnt lgkmcnt(0)" ::: "memory");
    __builtin_amdgcn_s_barrier();
    __builtin_amdgcn_sched_barrier(0);
}

// ---------------------------------------------------------------------------
// T0: pack weights: W_ihT[k][j] = W_ih[j][k]  (200x300)
//     wcat[k][j]: j<100 -> W_ti[j][k]; j==100 -> W_lgr[0][k]; else 0  (100x104)
// ---------------------------------------------------------------------------
__global__ void k_pack(const float* __restrict__ W_ih, const float* __restrict__ W_ti,
                       const float* __restrict__ W_lgr,
                       float* __restrict__ wT, float* __restrict__ wcat) {
    int idx = blockIdx.x * 256 + threadIdx.x;
    if (idx < E_ * H3_) {
        int k = idx / H3_, j = idx - k * H3_;
        wT[idx] = W_ih[j * E_ + k];
    }
    int i2 = idx - E_ * H3_;
    if (i2 >= 0 && i2 < H_ * 104) {
        int k = i2 / 104, j = i2 - k * 104;
        float v = 0.0f;
        if (j < H_) v = W_ti[j * H_ + k];
        else if (j == H_) v = W_lgr[k];
        wcat[i2] = v;
    }
}

// ---------------------------------------------------------------------------
// A: xp[row][j] = scale(row) * dot(emb[txt[row]], W_ih[j]) + b_ih[j]
// v2: float4 staging, W double-buffered in 16-k-row tiles with register
// prefetch (1 light barrier/iter), parallel row-norm. ~69 KB LDS -> 2 blk/CU.
// ---------------------------------------------------------------------------
__global__ __launch_bounds__(320) void k_embgemm(
        const int* __restrict__ txt, const float* __restrict__ emb,
        const float* __restrict__ wT, const float* __restrict__ b_ih,
        float* __restrict__ xp) {
    __shared__ __align__(16) float A_lds[E_ * 36];            // 28.8 KB [k][r]
    __shared__ __align__(16) float W_lds[2][16 * WSTRIDE];    // 38.9 KB [buf][kk][j]
    __shared__ float pp_lds[10][32];
    __shared__ float scale_lds[32];

    int tid = threadIdx.x;
    int base = blockIdx.x * 32;

    // ---- stage A: 32 rows x 50 float4, transpose into [k][r] (stride 36)
#pragma unroll
    for (int L = 0; L < 5; ++L) {
        int q = tid + 320 * L;            // 0..1599
        int r = q / 50, k4 = q % 50;
        int row = txt[base + r];
        float4 v = ((const float4*)(emb + (size_t)row * E_))[k4];
        int k = k4 * 4;
        A_lds[(k + 0) * 36 + r] = v.x;
        A_lds[(k + 1) * 36 + r] = v.y;
        A_lds[(k + 2) * 36 + r] = v.z;
        A_lds[(k + 3) * 36 + r] = v.w;
    }
    // ---- stage W tile 0 (k rows 0..15): 1200 float4
#pragma unroll
    for (int L = 0; L < 4; ++L) {
        int f = tid + 320 * L;
        if (f < 16 * 75) {
            int kl = f / 75, j4 = f % 75;
            float4 v = ((const float4*)wT)[kl * 75 + j4];
            *(float4*)&W_lds[0][kl * WSTRIDE + j4 * 4] = v;
        }
    }
    __syncthreads();

    // ---- parallel row norms: 10 k-slices x 32 rows
    {
        int r = tid % 32, s = tid / 32;   // s in 0..9
        float ss = 0.f;
        for (int k = s * 20; k < s * 20 + 20; ++k) {
            float v = A_lds[k * 36 + r];
            ss = fmaf(v, v, ss);
        }
        pp_lds[s][r] = ss;
    }
    __syncthreads();
    if (tid < 32) {
        float ss = 0.f;
#pragma unroll
        for (int s = 0; s < 10; ++s) ss += pp_lds[s][tid];
        float n = sqrtf(ss);
        scale_lds[tid] = (n > 1.0f) ? (1.0f / (n + 1e-7f)) : 1.0f;
    }

    int c = tid % 80, g = tid / 80;
    float4 acc[8];
#pragma unroll
    for (int i = 0; i < 8; ++i) acc[i] = make_float4(0.f, 0.f, 0.f, 0.f);

    const int NT = 13;  // 12 tiles of 16 k-rows + 1 tile of 8
    for (int ic = 0; ic < NT; ++ic) {
        int KC = (ic == 12) ? 8 : 16;
        int cur = ic & 1;

        // prefetch next W tile into registers (in flight during compute)
        float4 pf0, pf1, pf2, pf3;
        int nKC = 0;
        if (ic + 1 < NT) {
            nKC = (ic + 1 == 12) ? 8 : 16;
            const float4* src = ((const float4*)wT) + (ic + 1) * 16 * 75;
            int f0 = tid;
            if (f0 < nKC * 75) pf0 = src[f0];
            int f1 = tid + 320;
            if (f1 < nKC * 75) pf1 = src[f1];
            int f2 = tid + 640;
            if (f2 < nKC * 75) pf2 = src[f2];
            int f3 = tid + 960;
            if (f3 < nKC * 75) pf3 = src[f3];
        }

        if (c < 75) {
            for (int kk = 0; kk < KC; ++kk) {
                int k = ic * 16 + kk;
                float4 wv = *(const float4*)&W_lds[cur][kk * WSTRIDE + c * 4];
                float4 a0 = *(const float4*)&A_lds[k * 36 + g * 8];
                float4 a1 = *(const float4*)&A_lds[k * 36 + g * 8 + 4];
                fma4(acc[0], a0.x, wv); fma4(acc[1], a0.y, wv);
                fma4(acc[2], a0.z, wv); fma4(acc[3], a0.w, wv);
                fma4(acc[4], a1.x, wv); fma4(acc[5], a1.y, wv);
                fma4(acc[6], a1.z, wv); fma4(acc[7], a1.w, wv);
            }
        }

        // write prefetched tile to the alternate buffer
        if (ic + 1 < NT) {
            int f0 = tid;
            if (f0 < nKC * 75) *(float4*)&W_lds[cur ^ 1][(f0 / 75) * WSTRIDE + (f0 % 75) * 4] = pf0;
            int f1 = tid + 320;
            if (f1 < nKC * 75) *(float4*)&W_lds[cur ^ 1][(f1 / 75) * WSTRIDE + (f1 % 75) * 4] = pf1;
            int f2 = tid + 640;
            if (f2 < nKC * 75) *(float4*)&W_lds[cur ^ 1][(f2 / 75) * WSTRIDE + (f2 % 75) * 4] = pf2;
            int f3 = tid + 960;
            if (f3 < nKC * 75) *(float4*)&W_lds[cur ^ 1][(f3 / 75) * WSTRIDE + (f3 % 75) * 4] = pf3;
        }
        ldsbar();
    }

    if (c < 75) {
        float4 bv = *(const float4*)&b_ih[c * 4];
#pragma unroll
        for (int rr = 0; rr < 8; ++rr) {
            int r = g * 8 + rr;
            float s = scale_lds[r];
            float4 res;
            res.x = fmaf(acc[rr].x, s, bv.x);
            res.y = fmaf(acc[rr].y, s, bv.y);
            res.z = fmaf(acc[rr].z, s, bv.z);
            res.w = fmaf(acc[rr].w, s, bv.w);
            *(float4*)&xp[(size_t)(base + r) * H3_ + c * 4] = res;
        }
    }
}

// ---------------------------------------------------------------------------
// B: GRU scan. 1 block per batch row, 640 threads (10 waves).
// SPLIT-ROW weights: thread (half,j) holds HALF of W_hh row j (13 float4,
// ~52 regs -> no spill possible). half0: k 0..51; half1: k 48..99 with w[0]
// zeroed (k 48..51 counted by half0). Partials combined via p_lds; gate
// thread j<100 reuses its own half0 partial from register.
// Two light barriers/step; rnn store + x prefetch stay in flight.
// ---------------------------------------------------------------------------
__global__ __launch_bounds__(640, 3)
void k_gru(
        const float* __restrict__ xp, const float* __restrict__ W_hh,
        const float* __restrict__ b_hh, float* __restrict__ rnn) {
    __shared__ __align__(16) float h_lds[104];
    __shared__ float p_lds[640];

    int tid = threadIdx.x;
    int half = (tid >= 320) ? 1 : 0;
    int j = tid - half * 320;          // row 0..319 (<300 active)
    int kb = half ? 48 : 0;
    int b = blockIdx.x;

    float4 w[13];
    if (j < H3_) {
        const float4* wr = (const float4*)(W_hh + (size_t)j * H_ + kb);
#pragma unroll
        for (int i = 0; i < 13; ++i) w[i] = wr[i];
        if (half) w[0] = make_float4(0.f, 0.f, 0.f, 0.f);
#pragma unroll
        for (int i = 0; i < 13; ++i) KEEP4(w[i]);
    } else {
#pragma unroll
        for (int i = 0; i < 13; ++i) w[i] = make_float4(0.f, 0.f, 0.f, 0.f);
    }

    float bhr = 0.f, bhz = 0.f, bhn = 0.f;
    if (tid < H_) { bhr = b_hh[tid]; bhz = b_hh[H_ + tid]; bhn = b_hh[2 * H_ + tid]; }

    if (tid < 104) h_lds[tid] = 0.0f;
    float hown = 0.0f;  // thread tid<100 keeps its own h[tid]

    const float* xpb = xp + (size_t)b * T_ * H3_;
    float* rnnb = rnn + (size_t)b * T_ * H_;
    float xr = 0.f, xz = 0.f, xn = 0.f;
    if (tid < H_) { xr = xpb[tid]; xz = xpb[H_ + tid]; xn = xpb[2 * H_ + tid]; }
    __syncthreads();

    for (int t = 0; t < T_; ++t) {
        float a0 = 0.f, a1 = 0.f, a2 = 0.f, a3 = 0.f;
#pragma unroll
        for (int i = 0; i < 13; ++i) {
            float4 hv = *(const float4*)&h_lds[kb + i * 4];  // broadcast read
            a0 = fmaf(w[i].x, hv.x, a0);
            a1 = fmaf(w[i].y, hv.y, a1);
            a2 = fmaf(w[i].z, hv.z, a2);
            a3 = fmaf(w[i].w, hv.w, a3);
        }
        float ownp = (a0 + a1) + (a2 + a3);
        if (j < H3_) p_lds[tid] = ownp;
        // prefetch next step's x (stays in flight across the barrier)
        float nxr = 0.f, nxz = 0.f, nxn = 0.f;
        if (tid < H_ && t + 1 < T_) {
            const float* xq = xpb + (size_t)(t + 1) * H3_;
            nxr = xq[tid]; nxz = xq[H_ + tid]; nxn = xq[2 * H_ + tid];
        }
        ldsbar();  // partials visible
        if (tid < H_) {
            float hr = ownp             + p_lds[320 + tid] + bhr;  // own row's half0
            float hz = p_lds[100 + tid] + p_lds[420 + tid] + bhz;
            float hn = p_lds[200 + tid] + p_lds[520 + tid] + bhn;
            float r = 1.0f / (1.0f + expf(-(xr + hr)));
            float z = 1.0f / (1.0f + expf(-(xz + hz)));
            float ng = tanhf(xn + r * hn);
            float hnew = (1.0f - z) * ng + z * hown;
            hown = hnew;
            h_lds[tid] = hnew;
            rnnb[(size_t)t * H_ + tid] = hnew;   // fire-and-forget
            xr = nxr; xz = nxz; xn = nxn;
        }
        ldsbar();  // h visible for next matvec
    }
}

// ---------------------------------------------------------------------------
// C: ti = rnn @ W_ti.T + b_ti ; lgr = rnn @ W_lgr[:, :H].T ; z = relu(att*mask)
// ---------------------------------------------------------------------------
__global__ __launch_bounds__(256) void k_post(
        const float* __restrict__ rnn, const float* __restrict__ wcat,
        const float* __restrict__ b_ti, const int* __restrict__ lens,
        float* __restrict__ ti, float* __restrict__ lgr, float* __restrict__ zr) {
    __shared__ __align__(16) float A_lds[H_ * 72];   // [k][r], stride 72 (28.8 KB)
    __shared__ __align__(16) float W_lds[H_ * 112];  // [k][j], stride 112 (44.8 KB)

    int tid = threadIdx.x;
    int base = blockIdx.x * 64;

    for (int idx = tid; idx < 64 * H_; idx += 256) {
        int r = idx / H_, k = idx - r * H_;
        A_lds[k * 72 + r] = rnn[(size_t)(base + r) * H_ + k];
    }
    for (int idx = tid; idx < H_ * 104; idx += 256) {
        int k = idx / 104, jj = idx - k * 104;
        W_lds[k * 112 + jj] = wcat[idx];
    }
    __syncthreads();

    if (tid < 64) {
        float ss = 0.f, sm = 0.f;
        for (int k = 0; k < H_; ++k) {
            float v = A_lds[k * 72 + tid];
            ss = fmaf(v, v, ss); sm += v;
        }
        int row = base + tid;
        int bb = row >> 9, tt = row & 511;
        float att = sm / (fmaxf(sqrtf(ss), 1e-12f) * 1000.0f);  // / (norm * sqrt(H) * H)
        zr[row] = (tt < lens[bb]) ? fmaxf(att, 0.0f) : 0.0f;
    }

    int c = tid % 32, g = tid / 32;
    float4 acc[8];
#pragma unroll
    for (int i = 0; i < 8; ++i) acc[i] = make_float4(0.f, 0.f, 0.f, 0.f);

    if (c < 26) {
        for (int k = 0; k < H_; ++k) {
            float4 wv = *(const float4*)&W_lds[k * 112 + c * 4];
            float4 a0 = *(const float4*)&A_lds[k * 72 + g * 8];
            float4 a1 = *(const float4*)&A_lds[k * 72 + g * 8 + 4];
            fma4(acc[0], a0.x, wv); fma4(acc[1], a0.y, wv);
            fma4(acc[2], a0.z, wv); fma4(acc[3], a0.w, wv);
            fma4(acc[4], a1.x, wv); fma4(acc[5], a1.y, wv);
            fma4(acc[6], a1.z, wv); fma4(acc[7], a1.w, wv);
        }
    }

    if (c < 25) {
        float4 bv = *(const float4*)&b_ti[c * 4];
#pragma unroll
        for (int rr = 0; rr < 8; ++rr) {
            int row = base + g * 8 + rr;
            float4 res;
            res.x = acc[rr].x + bv.x; res.y = acc[rr].y + bv.y;
            res.z = acc[rr].z + bv.z; res.w = acc[rr].w + bv.w;
            *(float4*)&ti[(size_t)row * H_ + c * 4] = res;
        }
    } else if (c == 25) {
#pragma unroll
        for (int rr = 0; rr < 8; ++rr) {
            int row = base + g * 8 + rr;
            lgr[row] = acc[rr].x;  // j == 100 column
        }
    }
}

// ---------------------------------------------------------------------------
// D: rec scan + final GEMV. 1 block per batch row, 256 threads (4 waves).
// SPLIT-ROW weights: thread (half,j) holds half of W_ts row j (13 float4).
// Only half1 writes partials to LDS; gate thread j<100 keeps its own half0
// partial in register. Gate dot wl·s pipelined via shfl_xor + parity red[].
// ---------------------------------------------------------------------------
__global__ __launch_bounds__(256, 1)
void k_rec(
        const float* __restrict__ ti, const float* __restrict__ lgr,
        const float* __restrict__ zr,
        const float* __restrict__ W_ts, const float* __restrict__ b_ts,
        const float* __restrict__ W_lgr, const float* __restrict__ b_lgr,
        const float* __restrict__ W_out, const float* __restrict__ b_out,
        float* __restrict__ out) {
    __shared__ __align__(16) float sA[104];
    __shared__ __align__(16) float sB[104];
    __shared__ float p_lds[256];
    __shared__ float red[2][2];   // [parity][wave]

    int tid = threadIdx.x;
    int half = (tid >= 128) ? 1 : 0;
    int j = tid - half * 128;      // row 0..127 (<100 active)
    int kb = half ? 48 : 0;
    int b = blockIdx.x;

    float4 w[13];
    if (j < H_) {
        const float4* wr = (const float4*)(W_ts + (size_t)j * H_ + kb);
#pragma unroll
        for (int i = 0; i < 13; ++i) w[i] = wr[i];
        if (half) w[0] = make_float4(0.f, 0.f, 0.f, 0.f);
#pragma unroll
        for (int i = 0; i < 13; ++i) KEEP4(w[i]);
    } else {
#pragma unroll
        for (int i = 0; i < 13; ++i) w[i] = make_float4(0.f, 0.f, 0.f, 0.f);
    }

    float bts = 0.f, wlj = 0.f;
    if (tid < H_) { bts = b_ts[tid]; wlj = W_lgr[H_ + tid]; }
    float blg = b_lgr[0];
    if (tid < 104) sA[tid] = 0.0f;
    if (tid < 4) ((float*)red)[tid] = 0.0f;
    float sown = 0.0f;

    size_t rb = (size_t)b * T_;
    float tiv = 0.f, zt = 0.f, lt = 0.f;
    if (tid < H_) tiv = ti[rb * H_ + tid];
    zt = zr[rb]; lt = lgr[rb];
    __syncthreads();

    float* rd = sA;
    float* wrb = sB;
    for (int t = 0; t < T_; ++t) {
        float a0 = 0.f, a1 = 0.f, a2 = 0.f, a3 = 0.f;
#pragma unroll
        for (int i = 0; i < 13; ++i) {
            float4 s4 = *(const float4*)&rd[kb + i * 4];   // broadcast
            a0 = fmaf(w[i].x, s4.x, a0); a1 = fmaf(w[i].y, s4.y, a1);
            a2 = fmaf(w[i].z, s4.z, a2); a3 = fmaf(w[i].w, s4.w, a3);
        }
        float ownp = (a0 + a1) + (a2 + a3);
        if (half && j < H_) p_lds[tid] = ownp;
        // prefetch next step's inputs (stay in flight across the barrier)
        float ntiv = 0.f, nzt = 0.f, nlt = 0.f;
        if (t + 1 < T_) {
            if (tid < H_) ntiv = ti[(rb + t + 1) * H_ + tid];
            nzt = zr[rb + t + 1]; nlt = lgr[rb + t + 1];
        }
        ldsbar();  // half1 partials visible
        float dot = red[t & 1][0] + red[t & 1][1];
        float part = 0.0f;
        if (tid < H_) {
            float sv = ownp + p_lds[128 + tid];
            float gate = 1.0f / (1.0f + expf(-(lt + dot + blg)));
            float ns = tanhf(tiv + gate * sv + bts);
            float snew = (1.0f - zt) * sown + zt * ns;
            sown = snew;
            wrb[tid] = snew;
            part = wlj * snew;   // partial of NEXT step's gate dot
        }
        tiv = ntiv; zt = nzt; lt = nlt;
#pragma unroll
        for (int off = 1; off < 64; off <<= 1) part += __shfl_xor(part, off, 64);
        if ((tid & 63) == 0 && tid < 128) red[(t + 1) & 1][tid >> 6] = part;
        ldsbar();  // state + red visible
        float* tmp = rd; rd = wrb; wrb = tmp;
    }

    if (tid < NC_) {
        float o = b_out[tid];
        for (int k = 0; k < H_; ++k) o = fmaf(rd[k], W_out[tid * H_ + k], o);
        out[b * NC_ + tid] = o;
    }
}

// ---------------------------------------------------------------------------
extern "C" void kernel_launch(void* const* d_in, const int* in_sizes, int n_in,
                              void* d_out, int out_size, void* d_ws, size_t ws_size,
                              hipStream_t stream) {
    const int*   txt   = (const int*)d_in[0];
    const int*   lens  = (const int*)d_in[1];
    const float* emb   = (const float*)d_in[2];
    const float* W_ih  = (const float*)d_in[3];
    const float* W_hh  = (const float*)d_in[4];
    const float* b_ih  = (const float*)d_in[5];
    const float* b_hh  = (const float*)d_in[6];
    const float* W_lgr = (const float*)d_in[7];
    const float* b_lgr = (const float*)d_in[8];
    const float* W_ts  = (const float*)d_in[9];
    const float* b_ts  = (const float*)d_in[10];
    const float* W_ti  = (const float*)d_in[11];
    const float* b_ti  = (const float*)d_in[12];
    const float* W_out = (const float*)d_in[13];
    const float* b_out = (const float*)d_in[14];

    float* ws   = (float*)d_ws;
    float* xp   = ws;                    // 39,321,600 floats (157 MB)
    float* rnn  = xp + 39321600;         // 13,107,200 floats (52 MB)
    float* lgrv = rnn + 13107200;        // 131,072
    float* zrv  = lgrv + 131072;         // 131,072
    float* wT   = zrv + 131072;          // 60,000
    float* wcat = wT + 60000;            // 10,400
    float* ti   = xp;                    // reuse xp region after GRU

    float* out = (float*)d_out;

    k_pack<<<276, 256, 0, stream>>>(W_ih, W_ti, W_lgr, wT, wcat);
    k_embgemm<<<4096, 320, 0, stream>>>(txt, emb, wT, b_ih, xp);
    k_gru<<<256, 640, 0, stream>>>(xp, W_hh, b_hh, rnn);
    k_post<<<2048, 256, 0, stream>>>(rnn, wcat, b_ti, lens, ti, lgrv, zrv);
    k_rec<<<256, 256, 0, stream>>>(ti, lgrv, zrv, W_ts, b_ts, W_lgr, b_lgr,
                                   W_out, b_out, out);
}

// Round 9
// 1440.540 us; speedup vs baseline: 1.6785x; 1.0607x over previous
//
#include <hip/hip_runtime.h>

// Problem constants
#define B_   256
#define T_   512
#define E_   200
#define H_   100
#define H3_  300
#define NC_  5

#define WSTRIDE 304   // W_lds row stride in floats (16B-aligned, breaks pow2)

__device__ __forceinline__ void fma4(float4& acc, float a, const float4& w) {
    acc.x = fmaf(a, w.x, acc.x);
    acc.y = fmaf(a, w.y, acc.y);
    acc.z = fmaf(a, w.z, acc.z);
    acc.w = fmaf(a, w.w, acc.w);
}

// Pin a float4 into registers (blocks remat/re-sinking of the producing load).
#define KEEP4(v) asm volatile("" : "+v"((v).x), "+v"((v).y), "+v"((v).z), "+v"((v).w))

// Light barrier: drain LDS ops only (NOT global/vmcnt), then raw s_barrier.
__device__ __forceinline__ void ldsbar() {
    asm volatile("s_waitcnt lgkmcnt(0)" ::: "memory");
    __builtin_amdgcn_s_barrier();
    __builtin_amdgcn_sched_barrier(0);
}

// SGPR broadcast of a lane-held value: v_readlane (lane index is a literal
// under full unroll). Moves the scan's broadcast traffic off the LDS pipe
// onto the (4x wider) VALU/SALU path.
__device__ __forceinline__ float rlane(float v, int l) {
    return __uint_as_float(__builtin_amdgcn_readlane(__float_as_uint(v), (unsigned)l));
}

// dot of this thread's weight segment (N4 float4s) with the wave-lane-held
// vector segment hreg (lane i holds seg[i]).
template<int N4>
__device__ __forceinline__ float dotseg(const float4 (&w)[9], float hreg) {
    float a0 = 0.f, a1 = 0.f, a2 = 0.f, a3 = 0.f;
#pragma unroll
    for (int q = 0; q < N4; ++q) {
        a0 = fmaf(w[q].x, rlane(hreg, 4 * q + 0), a0);
        a1 = fmaf(w[q].y, rlane(hreg, 4 * q + 1), a1);
        a2 = fmaf(w[q].z, rlane(hreg, 4 * q + 2), a2);
        a3 = fmaf(w[q].w, rlane(hreg, 4 * q + 3), a3);
    }
    return (a0 + a1) + (a2 + a3);
}

// ---------------------------------------------------------------------------
// T0: pack weights: W_ihT[k][j] = W_ih[j][k]  (200x300)
//     wcat[k][j]: j<100 -> W_ti[j][k]; j==100 -> W_lgr[0][k]; else 0  (100x104)
// ---------------------------------------------------------------------------
__global__ void k_pack(const float* __restrict__ W_ih, const float* __restrict__ W_ti,
                       const float* __restrict__ W_lgr,
                       float* __restrict__ wT, float* __restrict__ wcat) {
    int idx = blockIdx.x * 256 + threadIdx.x;
    if (idx < E_ * H3_) {
        int k = idx / H3_, j = idx - k * H3_;
        wT[idx] = W_ih[j * E_ + k];
    }
    int i2 = idx - E_ * H3_;
    if (i2 >= 0 && i2 < H_ * 104) {
        int k = i2 / 104, j = i2 - k * 104;
        float v = 0.0f;
        if (j < H_) v = W_ti[j * H_ + k];
        else if (j == H_) v = W_lgr[k];
        wcat[i2] = v;
    }
}

// ---------------------------------------------------------------------------
// A: xp[row][j] = scale(row) * dot(emb[txt[row]], W_ih[j]) + b_ih[j]
// v2: float4 staging, W double-buffered in 16-k-row tiles with register
// prefetch (1 light barrier/iter), parallel row-norm. ~69 KB LDS -> 2 blk/CU.
// ---------------------------------------------------------------------------
__global__ __launch_bounds__(320) void k_embgemm(
        const int* __restrict__ txt, const float* __restrict__ emb,
        const float* __restrict__ wT, const float* __restrict__ b_ih,
        float* __restrict__ xp) {
    __shared__ __align__(16) float A_lds[E_ * 36];            // 28.8 KB [k][r]
    __shared__ __align__(16) float W_lds[2][16 * WSTRIDE];    // 38.9 KB [buf][kk][j]
    __shared__ float pp_lds[10][32];
    __shared__ float scale_lds[32];

    int tid = threadIdx.x;
    int base = blockIdx.x * 32;

    // ---- stage A: 32 rows x 50 float4, transpose into [k][r] (stride 36)
#pragma unroll
    for (int L = 0; L < 5; ++L) {
        int q = tid + 320 * L;            // 0..1599
        int r = q / 50, k4 = q % 50;
        int row = txt[base + r];
        float4 v = ((const float4*)(emb + (size_t)row * E_))[k4];
        int k = k4 * 4;
        A_lds[(k + 0) * 36 + r] = v.x;
        A_lds[(k + 1) * 36 + r] = v.y;
        A_lds[(k + 2) * 36 + r] = v.z;
        A_lds[(k + 3) * 36 + r] = v.w;
    }
    // ---- stage W tile 0 (k rows 0..15): 1200 float4
#pragma unroll
    for (int L = 0; L < 4; ++L) {
        int f = tid + 320 * L;
        if (f < 16 * 75) {
            int kl = f / 75, j4 = f % 75;
            float4 v = ((const float4*)wT)[kl * 75 + j4];
            *(float4*)&W_lds[0][kl * WSTRIDE + j4 * 4] = v;
        }
    }
    __syncthreads();

    // ---- parallel row norms: 10 k-slices x 32 rows
    {
        int r = tid % 32, s = tid / 32;   // s in 0..9
        float ss = 0.f;
        for (int k = s * 20; k < s * 20 + 20; ++k) {
            float v = A_lds[k * 36 + r];
            ss = fmaf(v, v, ss);
        }
        pp_lds[s][r] = ss;
    }
    __syncthreads();
    if (tid < 32) {
        float ss = 0.f;
#pragma unroll
        for (int s = 0; s < 10; ++s) ss += pp_lds[s][tid];
        float n = sqrtf(ss);
        scale_lds[tid] = (n > 1.0f) ? (1.0f / (n + 1e-7f)) : 1.0f;
    }

    int c = tid % 80, g = tid / 80;
    float4 acc[8];
#pragma unroll
    for (int i = 0; i < 8; ++i) acc[i] = make_float4(0.f, 0.f, 0.f, 0.f);

    const int NT = 13;  // 12 tiles of 16 k-rows + 1 tile of 8
    for (int ic = 0; ic < NT; ++ic) {
        int KC = (ic == 12) ? 8 : 16;
        int cur = ic & 1;

        // prefetch next W tile into registers (in flight during compute)
        float4 pf0, pf1, pf2, pf3;
        int nKC = 0;
        if (ic + 1 < NT) {
            nKC = (ic + 1 == 12) ? 8 : 16;
            const float4* src = ((const float4*)wT) + (ic + 1) * 16 * 75;
            int f0 = tid;
            if (f0 < nKC * 75) pf0 = src[f0];
            int f1 = tid + 320;
            if (f1 < nKC * 75) pf1 = src[f1];
            int f2 = tid + 640;
            if (f2 < nKC * 75) pf2 = src[f2];
            int f3 = tid + 960;
            if (f3 < nKC * 75) pf3 = src[f3];
        }

        if (c < 75) {
            for (int kk = 0; kk < KC; ++kk) {
                int k = ic * 16 + kk;
                float4 wv = *(const float4*)&W_lds[cur][kk * WSTRIDE + c * 4];
                float4 a0 = *(const float4*)&A_lds[k * 36 + g * 8];
                float4 a1 = *(const float4*)&A_lds[k * 36 + g * 8 + 4];
                fma4(acc[0], a0.x, wv); fma4(acc[1], a0.y, wv);
                fma4(acc[2], a0.z, wv); fma4(acc[3], a0.w, wv);
                fma4(acc[4], a1.x, wv); fma4(acc[5], a1.y, wv);
                fma4(acc[6], a1.z, wv); fma4(acc[7], a1.w, wv);
            }
        }

        // write prefetched tile to the alternate buffer
        if (ic + 1 < NT) {
            int f0 = tid;
            if (f0 < nKC * 75) *(float4*)&W_lds[cur ^ 1][(f0 / 75) * WSTRIDE + (f0 % 75) * 4] = pf0;
            int f1 = tid + 320;
            if (f1 < nKC * 75) *(float4*)&W_lds[cur ^ 1][(f1 / 75) * WSTRIDE + (f1 % 75) * 4] = pf1;
            int f2 = tid + 640;
            if (f2 < nKC * 75) *(float4*)&W_lds[cur ^ 1][(f2 / 75) * WSTRIDE + (f2 % 75) * 4] = pf2;
            int f3 = tid + 960;
            if (f3 < nKC * 75) *(float4*)&W_lds[cur ^ 1][(f3 / 75) * WSTRIDE + (f3 % 75) * 4] = pf3;
        }
        ldsbar();
    }

    if (c < 75) {
        float4 bv = *(const float4*)&b_ih[c * 4];
#pragma unroll
        for (int rr = 0; rr < 8; ++rr) {
            int r = g * 8 + rr;
            float s = scale_lds[r];
            float4 res;
            res.x = fmaf(acc[rr].x, s, bv.x);
            res.y = fmaf(acc[rr].y, s, bv.y);
            res.z = fmaf(acc[rr].z, s, bv.z);
            res.w = fmaf(acc[rr].w, s, bv.w);
            *(float4*)&xp[(size_t)(base + r) * H3_ + c * 4] = res;
        }
    }
}

// ---------------------------------------------------------------------------
// B: GRU scan. 1 block per batch row, 960 threads (15 waves).
// THIRD-ROW split: thread (third,j) holds a 36/32-float segment of W_hh row j
// (9 float4 -> ~60 VGPR total, under the RA's 64-reg occupancy budget: no
// spill). h broadcast via ONE ds_read_b32/wave (lane l holds h[kb+l]) +
// v_readlane SGPR operands — moves broadcast cost off the single LDS pipe
// onto the 4 SIMDs. Two light barriers/step.
// ---------------------------------------------------------------------------
__global__ __launch_bounds__(960)
__attribute__((amdgpu_waves_per_eu(1, 4)))
void k_gru(
        const float* __restrict__ xp, const float* __restrict__ W_hh,
        const float* __restrict__ b_hh, float* __restrict__ rnn) {
    __shared__ float h_lds[104];
    __shared__ float p_lds[960];

    int tid = threadIdx.x;
    int lane = tid & 63;
    int third = tid / 320;                 // 5 waves per third -> wave-uniform
    int j = tid - third * 320;             // row (active if < 300)
    int kb = (third == 0) ? 0 : (third == 1 ? 36 : 68);
    int seg = (third == 0) ? 36 : 32;
    int seg4 = (third == 0) ? 9 : 8;
    int b = blockIdx.x;

    float4 w4[9];
#pragma unroll
    for (int q = 0; q < 9; ++q) w4[q] = make_float4(0.f, 0.f, 0.f, 0.f);
    if (j < H3_) {
        const float4* wr = (const float4*)(W_hh + (size_t)j * H_ + kb);
#pragma unroll
        for (int q = 0; q < 9; ++q) if (q < seg4) w4[q] = wr[q];
    }
#pragma unroll
    for (int q = 0; q < 9; ++q) KEEP4(w4[q]);

    float bhr = 0.f, bhz = 0.f, bhn = 0.f;
    if (tid < H_) { bhr = b_hh[tid]; bhz = b_hh[H_ + tid]; bhn = b_hh[2 * H_ + tid]; }

    const float* xpb = xp + (size_t)b * T_ * H3_;
    float* rnnb = rnn + (size_t)b * T_ * H_;
    float xr = 0.f, xz = 0.f, xn = 0.f;
    if (tid < H_) { xr = xpb[tid]; xz = xpb[H_ + tid]; xn = xpb[2 * H_ + tid]; }

    float hreg = 0.f;   // lane-held h segment value (h starts at 0)
    float hown = 0.f;   // gate thread's own h[tid]

    for (int t = 0; t < T_; ++t) {
        float p = (third == 0) ? dotseg<9>(w4, hreg) : dotseg<8>(w4, hreg);
        if (j < H3_) p_lds[tid] = p;
        // prefetch next step's x (stays in flight across the barriers)
        float nxr = 0.f, nxz = 0.f, nxn = 0.f;
        if (tid < H_ && t + 1 < T_) {
            const float* xq = xpb + (size_t)(t + 1) * H3_;
            nxr = xq[tid]; nxz = xq[H_ + tid]; nxn = xq[2 * H_ + tid];
        }
        ldsbar();  // partials visible
        if (tid < H_) {
            float hr = p + p_lds[320 + tid] + p_lds[640 + tid] + bhr;           // row tid
            float hz = p_lds[100 + tid] + p_lds[420 + tid] + p_lds[740 + tid] + bhz;  // row 100+tid
            float hn = p_lds[200 + tid] + p_lds[520 + tid] + p_lds[840 + tid] + bhn;  // row 200+tid
            float r = 1.0f / (1.0f + expf(-(xr + hr)));
            float z = 1.0f / (1.0f + expf(-(xz + hz)));
            float ng = tanhf(xn + r * hn);
            float hnew = (1.0f - z) * ng + z * hown;
            hown = hnew;
            h_lds[tid] = hnew;
            rnnb[(size_t)t * H_ + tid] = hnew;   // fire-and-forget
            xr = nxr; xz = nxz; xn = nxn;
        }
        ldsbar();  // h visible
        hreg = (lane < seg) ? h_lds[kb + lane] : 0.f;  // 1 ds_read_b32 / wave
    }
}

// ---------------------------------------------------------------------------
// C: ti = rnn @ W_ti.T + b_ti ; lgr = rnn @ W_lgr[:, :H].T ; z = relu(att*mask)
// ---------------------------------------------------------------------------
__global__ __launch_bounds__(256) void k_post(
        const float* __restrict__ rnn, const float* __restrict__ wcat,
        const float* __restrict__ b_ti, const int* __restrict__ lens,
        float* __restrict__ ti, float* __restrict__ lgr, float* __restrict__ zr) {
    __shared__ __align__(16) float A_lds[H_ * 72];   // [k][r], stride 72 (28.8 KB)
    __shared__ __align__(16) float W_lds[H_ * 112];  // [k][j], stride 112 (44.8 KB)

    int tid = threadIdx.x;
    int base = blockIdx.x * 64;

    for (int idx = tid; idx < 64 * H_; idx += 256) {
        int r = idx / H_, k = idx - r * H_;
        A_lds[k * 72 + r] = rnn[(size_t)(base + r) * H_ + k];
    }
    for (int idx = tid; idx < H_ * 104; idx += 256) {
        int k = idx / 104, jj = idx - k * 104;
        W_lds[k * 112 + jj] = wcat[idx];
    }
    __syncthreads();

    if (tid < 64) {
        float ss = 0.f, sm = 0.f;
        for (int k = 0; k < H_; ++k) {
            float v = A_lds[k * 72 + tid];
            ss = fmaf(v, v, ss); sm += v;
        }
        int row = base + tid;
        int bb = row >> 9, tt = row & 511;
        float att = sm / (fmaxf(sqrtf(ss), 1e-12f) * 1000.0f);  // / (norm * sqrt(H) * H)
        zr[row] = (tt < lens[bb]) ? fmaxf(att, 0.0f) : 0.0f;
    }

    int c = tid % 32, g = tid / 32;
    float4 acc[8];
#pragma unroll
    for (int i = 0; i < 8; ++i) acc[i] = make_float4(0.f, 0.f, 0.f, 0.f);

    if (c < 26) {
        for (int k = 0; k < H_; ++k) {
            float4 wv = *(const float4*)&W_lds[k * 112 + c * 4];
            float4 a0 = *(const float4*)&A_lds[k * 72 + g * 8];
            float4 a1 = *(const float4*)&A_lds[k * 72 + g * 8 + 4];
            fma4(acc[0], a0.x, wv); fma4(acc[1], a0.y, wv);
            fma4(acc[2], a0.z, wv); fma4(acc[3], a0.w, wv);
            fma4(acc[4], a1.x, wv); fma4(acc[5], a1.y, wv);
            fma4(acc[6], a1.z, wv); fma4(acc[7], a1.w, wv);
        }
    }

    if (c < 25) {
        float4 bv = *(const float4*)&b_ti[c * 4];
#pragma unroll
        for (int rr = 0; rr < 8; ++rr) {
            int row = base + g * 8 + rr;
            float4 res;
            res.x = acc[rr].x + bv.x; res.y = acc[rr].y + bv.y;
            res.z = acc[rr].z + bv.z; res.w = acc[rr].w + bv.w;
            *(float4*)&ti[(size_t)row * H_ + c * 4] = res;
        }
    } else if (c == 25) {
#pragma unroll
        for (int rr = 0; rr < 8; ++rr) {
            int row = base + g * 8 + rr;
            lgr[row] = acc[rr].x;  // j == 100 column
        }
    }
}

// ---------------------------------------------------------------------------
// D: rec scan + final GEMV. 1 block per batch row, 384 threads (6 waves).
// THIRD-ROW split of W_ts (9 float4/thread) + readlane broadcast of state.
// Gate dot wl·s pipelined via shfl_xor + parity red[]. Single state buffer
// (matvec reads the lane-held copy, not LDS).
// ---------------------------------------------------------------------------
__global__ __launch_bounds__(384)
__attribute__((amdgpu_waves_per_eu(1, 4)))
void k_rec(
        const float* __restrict__ ti, const float* __restrict__ lgr,
        const float* __restrict__ zr,
        const float* __restrict__ W_ts, const float* __restrict__ b_ts,
        const float* __restrict__ W_lgr, const float* __restrict__ b_lgr,
        const float* __restrict__ W_out, const float* __restrict__ b_out,
        float* __restrict__ out) {
    __shared__ float st_lds[104];
    __shared__ float p_lds[384];
    __shared__ float red[2][2];   // [parity][wave]

    int tid = threadIdx.x;
    int lane = tid & 63;
    int third = tid / 128;                 // 2 waves per third -> wave-uniform
    int j = tid - third * 128;             // row (active if < 100)
    int kb = (third == 0) ? 0 : (third == 1 ? 36 : 68);
    int seg = (third == 0) ? 36 : 32;
    int seg4 = (third == 0) ? 9 : 8;
    int b = blockIdx.x;

    float4 w4[9];
#pragma unroll
    for (int q = 0; q < 9; ++q) w4[q] = make_float4(0.f, 0.f, 0.f, 0.f);
    if (j < H_) {
        const float4* wr = (const float4*)(W_ts + (size_t)j * H_ + kb);
#pragma unroll
        for (int q = 0; q < 9; ++q) if (q < seg4) w4[q] = wr[q];
    }
#pragma unroll
    for (int q = 0; q < 9; ++q) KEEP4(w4[q]);

    float bts = 0.f, wlj = 0.f;
    if (tid < H_) { bts = b_ts[tid]; wlj = W_lgr[H_ + tid]; }
    float blg = b_lgr[0];
    if (tid < 4) ((float*)red)[tid] = 0.0f;
    float sown = 0.0f;
    float sreg = 0.0f;

    size_t rb = (size_t)b * T_;
    float tiv = 0.f, zt = 0.f, lt = 0.f;
    if (tid < H_) tiv = ti[rb * H_ + tid];
    zt = zr[rb]; lt = lgr[rb];

    for (int t = 0; t < T_; ++t) {
        float p = (third == 0) ? dotseg<9>(w4, sreg) : dotseg<8>(w4, sreg);
        if (j < H_) p_lds[tid] = p;
        // prefetch next step's inputs (stay in flight across the barrier)
        float ntiv = 0.f, nzt = 0.f, nlt = 0.f;
        if (t + 1 < T_) {
            if (tid < H_) ntiv = ti[(rb + t + 1) * H_ + tid];
            nzt = zr[rb + t + 1]; nlt = lgr[rb + t + 1];
        }
        ldsbar();  // partials + red visible
        float dot = red[t & 1][0] + red[t & 1][1];
        float part = 0.0f;
        if (tid < H_) {
            float sv = p + p_lds[128 + tid] + p_lds[256 + tid];
            float gate = 1.0f / (1.0f + expf(-(lt + dot + blg)));
            float ns = tanhf(tiv + gate * sv + bts);
            float snew = (1.0f - zt) * sown + zt * ns;
            sown = snew;
            st_lds[tid] = snew;
            part = wlj * snew;   // partial of NEXT step's gate dot
        }
        tiv = ntiv; zt = nzt; lt = nlt;
        if (tid < 128) {         // waves 0,1 only (contain all gate threads)
#pragma unroll
            for (int off = 1; off < 64; off <<= 1) part += __shfl_xor(part, off, 64);
            if ((tid & 63) == 0) red[(t + 1) & 1][tid >> 6] = part;
        }
        ldsbar();  // state + red visible
        sreg = (lane < seg) ? st_lds[kb + lane] : 0.f;
    }

    if (tid < NC_) {
        float o = b_out[tid];
        for (int k = 0; k < H_; ++k) o = fmaf(st_lds[k], W_out[tid * H_ + k], o);
        out[b * NC_ + tid] = o;
    }
}

// ---------------------------------------------------------------------------
extern "C" void kernel_launch(void* const* d_in, const int* in_sizes, int n_in,
                              void* d_out, int out_size, void* d_ws, size_t ws_size,
                              hipStream_t stream) {
    const int*   txt   = (const int*)d_in[0];
    const int*   lens  = (const int*)d_in[1];
    const float* emb   = (const float*)d_in[2];
    const float* W_ih  = (const float*)d_in[3];
    const float* W_hh  = (const float*)d_in[4];
    const float* b_ih  = (const float*)d_in[5];
    const float* b_hh  = (const float*)d_in[6];
    const float* W_lgr = (const float*)d_in[7];
    const float* b_lgr = (const float*)d_in[8];
    const float* W_ts  = (const float*)d_in[9];
    const float* b_ts  = (const float*)d_in[10];
    const float* W_ti  = (const float*)d_in[11];
    const float* b_ti  = (const float*)d_in[12];
    const float* W_out = (const float*)d_in[13];
    const float* b_out = (const float*)d_in[14];

    float* ws   = (float*)d_ws;
    float* xp   = ws;                    // 39,321,600 floats (157 MB)
    float* rnn  = xp + 39321600;         // 13,107,200 floats (52 MB)
    float* lgrv = rnn + 13107200;        // 131,072
    float* zrv  = lgrv + 131072;         // 131,072
    float* wT   = zrv + 131072;          // 60,000
    float* wcat = wT + 60000;            // 10,400
    float* ti   = xp;                    // reuse xp region after GRU

    float* out = (float*)d_out;

    k_pack<<<276, 256, 0, stream>>>(W_ih, W_ti, W_lgr, wT, wcat);
    k_embgemm<<<4096, 320, 0, stream>>>(txt, emb, wT, b_ih, xp);
    k_gru<<<256, 960, 0, stream>>>(xp, W_hh, b_hh, rnn);
    k_post<<<2048, 256, 0, stream>>>(rnn, wcat, b_ti, lens, ti, lgrv, zrv);
    k_rec<<<256, 384, 0, stream>>>(ti, lgrv, zrv, W_ts, b_ts, W_lgr, b_lgr,
                                   W_out, b_out, out);
}